// Round 3
// 3414.035 us; speedup vs baseline: 3.2786x; 3.2786x over previous
//
#include <hip/hip_runtime.h>
#include <hip/hip_bf16.h>
#include <math.h>

using u16 = unsigned short;
using u32 = unsigned int;

typedef __attribute__((ext_vector_type(8))) short s8v;    // 8 x bf16 bits (4 VGPRs)
typedef __attribute__((ext_vector_type(4))) float f4v;    // MFMA acc

__device__ __forceinline__ float bf2f(u16 u) {
    u32 x = ((u32)u) << 16;
    return __builtin_bit_cast(float, x);
}
__device__ __forceinline__ u16 f2bf(float f) {
    u32 x = __builtin_bit_cast(u32, f);
    x += 0x7fffu + ((x >> 16) & 1u);
    return (u16)(x >> 16);
}

__device__ __forceinline__ f4v mfma_bf16(s8v a, s8v b, f4v c) {
    return __builtin_amdgcn_mfma_f32_16x16x32_bf16(a, b, c, 0, 0, 0);
}

// ---------------------------------------------------------------- GEMM ----
// C[M,N] = A[M,K] @ B[K,N] via mfma_f32_16x16x32_bf16.
// AMODE/BMODE: 0 = operand is bf16 (u16) in memory, used directly.
//              2 = operand is f32; split into bf16 hi+lo (near-f32 precision).
// f32 accumulate; C f32 or bf16; optional ELU epilogue. Bounds-checked.
// Tile: BM=128, BN=64, BK=32. 256 threads = 4 waves in 2x2 wave grid;
// each wave computes 64x32 via 4x2 fragments of 16x16.
template<int AMODE, int BMODE, bool DO_ELU, bool OUT_F32>
__global__ __launch_bounds__(256) void mgemm(
    const void* __restrict__ Av, const void* __restrict__ Bv,
    void* __restrict__ Cv, int M, int N, int K)
{
    constexpr int BM = 128, BN = 64, BK = 32;
    constexpr int KP = BK + 8;              // 40 elems = 80B row stride (16B aligned)
    constexpr bool ASP = (AMODE == 2);
    constexpr bool BSP = (BMODE == 2);
    constexpr int NA = ASP ? 2 : 1;
    constexpr int NB = BSP ? 2 : 1;

    __shared__ __align__(16) u16 As[NA][BM][KP];
    __shared__ __align__(16) u16 Bs[NB][BN][KP];

    const int bm0 = blockIdx.y * BM, bn0 = blockIdx.x * BN;
    const int tid = threadIdx.x;
    const int lane = tid & 63;
    const int wave = tid >> 6;
    const int wr = wave >> 1;               // wave row 0..1 (64 rows each)
    const int wc = wave & 1;                // wave col 0..1 (32 cols each)
    const int lr = lane & 15;               // fragment row/col within 16
    const int kb = (lane >> 4) * 8;         // k-offset of this lane's 8 elems

    f4v acc[4][2] = {};

    for (int k0 = 0; k0 < K; k0 += BK) {
        // ---- stage A tile: As[s][m][k] = A[bm0+m][k0+k] (bf16 hi/lo) ----
        for (int u = tid; u < BM * (BK / 8); u += 256) {
            const int row = u >> 2;
            const int ks = (u & 3) * 8;
            const int gm = bm0 + row, gk = k0 + ks;
            if constexpr (AMODE == 0) {
                const u16* Ab = (const u16*)Av;
                s8v v = {};
                if (gm < M) {
                    if (gk + 8 <= K) {
                        v = *(const s8v*)(Ab + (size_t)gm * K + gk);
                    } else if (gk < K) {
#pragma unroll
                        for (int j = 0; j < 8; j++)
                            ((u16*)&v)[j] = (gk + j < K) ? Ab[(size_t)gm * K + gk + j] : (u16)0;
                    }
                }
                *(s8v*)&As[0][row][ks] = v;
            } else {
                const float* Af = (const float*)Av;
                float v[8] = {0.f,0.f,0.f,0.f,0.f,0.f,0.f,0.f};
                if (gm < M) {
                    if (gk + 8 <= K) {
                        const float4* p = (const float4*)(Af + (size_t)gm * K + gk);
                        float4 x0 = p[0], x1 = p[1];
                        v[0]=x0.x; v[1]=x0.y; v[2]=x0.z; v[3]=x0.w;
                        v[4]=x1.x; v[5]=x1.y; v[6]=x1.z; v[7]=x1.w;
                    } else if (gk < K) {
#pragma unroll
                        for (int j = 0; j < 8; j++)
                            if (gk + j < K) v[j] = Af[(size_t)gm * K + gk + j];
                    }
                }
                s8v hi, lo;
#pragma unroll
                for (int j = 0; j < 8; j++) {
                    u16 h = f2bf(v[j]);
                    ((u16*)&hi)[j] = h;
                    ((u16*)&lo)[j] = f2bf(v[j] - bf2f(h));
                }
                *(s8v*)&As[0][row][ks] = hi;
                *(s8v*)&As[1][row][ks] = lo;
            }
        }
        // ---- stage B tile transposed: Bs[s][n][k] = B[k0+k][bn0+n] ----
        {
            const int k = tid >> 3;         // 0..31
            const int p = tid & 7;          // n-segment
            const int n0 = p * 8;
            const int gk = k0 + k;
            if constexpr (BMODE == 0) {
                const u16* Bb = (const u16*)Bv;
                s8v v = {};
                if (gk < K) {
                    if (bn0 + n0 + 8 <= N) {
                        v = *(const s8v*)(Bb + (size_t)gk * N + bn0 + n0);
                    } else {
#pragma unroll
                        for (int j = 0; j < 8; j++)
                            ((u16*)&v)[j] = (bn0 + n0 + j < N) ? Bb[(size_t)gk * N + bn0 + n0 + j] : (u16)0;
                    }
                }
                // rotation by p avoids same-bank scalar-write conflicts
#pragma unroll
                for (int jj = 0; jj < 8; jj++) {
                    int j = (jj + p) & 7;
                    Bs[0][n0 + j][k] = ((u16*)&v)[j];
                }
            } else {
                const float* Bf = (const float*)Bv;
                float v[8] = {0.f,0.f,0.f,0.f,0.f,0.f,0.f,0.f};
                if (gk < K) {
                    if (bn0 + n0 + 8 <= N) {
                        const float4* pp = (const float4*)(Bf + (size_t)gk * N + bn0 + n0);
                        float4 x0 = pp[0], x1 = pp[1];
                        v[0]=x0.x; v[1]=x0.y; v[2]=x0.z; v[3]=x0.w;
                        v[4]=x1.x; v[5]=x1.y; v[6]=x1.z; v[7]=x1.w;
                    } else {
#pragma unroll
                        for (int j = 0; j < 8; j++)
                            if (bn0 + n0 + j < N) v[j] = Bf[(size_t)gk * N + bn0 + n0 + j];
                    }
                }
#pragma unroll
                for (int jj = 0; jj < 8; jj++) {
                    int j = (jj + p) & 7;
                    u16 h = f2bf(v[j]);
                    Bs[0][n0 + j][k] = h;
                    Bs[1][n0 + j][k] = f2bf(v[j] - bf2f(h));
                }
            }
        }
        __syncthreads();

        // ---- fragments + MFMA ----
        s8v a0[4], a1[ASP ? 4 : 1];
        s8v b0[2], b1[BSP ? 2 : 1];
#pragma unroll
        for (int m = 0; m < 4; m++) {
            a0[m] = *(const s8v*)&As[0][wr * 64 + m * 16 + lr][kb];
            if constexpr (ASP) a1[m] = *(const s8v*)&As[1][wr * 64 + m * 16 + lr][kb];
        }
#pragma unroll
        for (int n = 0; n < 2; n++) {
            b0[n] = *(const s8v*)&Bs[0][wc * 32 + n * 16 + lr][kb];
            if constexpr (BSP) b1[n] = *(const s8v*)&Bs[1][wc * 32 + n * 16 + lr][kb];
        }
#pragma unroll
        for (int m = 0; m < 4; m++)
#pragma unroll
            for (int n = 0; n < 2; n++) {
                acc[m][n] = mfma_bf16(a0[m], b0[n], acc[m][n]);
                if constexpr (ASP) acc[m][n] = mfma_bf16(a1[m], b0[n], acc[m][n]);
                if constexpr (BSP) acc[m][n] = mfma_bf16(a0[m], b1[n], acc[m][n]);
            }
        __syncthreads();
    }

    // ---- epilogue: D row = 4*(lane>>4)+i, col = lane&15 ----
#pragma unroll
    for (int m = 0; m < 4; m++)
#pragma unroll
        for (int n = 0; n < 2; n++)
#pragma unroll
            for (int i = 0; i < 4; i++) {
                int gm = bm0 + wr * 64 + m * 16 + (lane >> 4) * 4 + i;
                int gn = bn0 + wc * 32 + n * 16 + lr;
                if (gm < M && gn < N) {
                    float val = acc[m][n][i];
                    if (DO_ELU) val = val > 0.f ? val : expm1f(val);
                    if (OUT_F32) ((float*)Cv)[(size_t)gm * N + gn] = val;
                    else         ((u16*)Cv)[(size_t)gm * N + gn] = f2bf(val);
                }
            }
}

// ------------------------------------------------------------- reduce ----
__device__ __forceinline__ float block_sum4(float v, float* red) {
#pragma unroll
    for (int off = 32; off; off >>= 1) v += __shfl_down(v, off);
    int w = threadIdx.x >> 6;
    if ((threadIdx.x & 63) == 0) red[w] = v;
    __syncthreads();
    float r = red[0] + red[1] + red[2] + red[3];
    __syncthreads();
    return r;
}
__device__ __forceinline__ float block_max4(float v, float* red) {
#pragma unroll
    for (int off = 32; off; off >>= 1) v = fmaxf(v, __shfl_down(v, off));
    int w = threadIdx.x >> 6;
    if ((threadIdx.x & 63) == 0) red[w] = v;
    __syncthreads();
    float r = fmaxf(fmaxf(red[0], red[1]), fmaxf(red[2], red[3]));
    __syncthreads();
    return r;
}

// ------------------------------------------------------------- scores ----
__global__ __launch_bounds__(256) void scores_kernel(
    const u16* __restrict__ Wh, int ld, int F, const float* __restrict__ a,
    float* __restrict__ s1, float* __restrict__ s2)
{
    __shared__ float red[4];
    int i = blockIdx.x, tid = threadIdx.x;
    float acc1 = 0.f, acc2 = 0.f;
    for (int f = tid; f < F; f += 256) {
        float w = bf2f(Wh[(size_t)i * ld + f]);
        acc1 += w * a[f];
        acc2 += w * a[F + f];
    }
    acc1 = block_sum4(acc1, red);
    acc2 = block_sum4(acc2, red);
    if (tid == 0) { s1[i] = acc1; s2[i] = acc2; }
}

// ---------------------------------------------------------------- att ----
__global__ __launch_bounds__(256) void att_kernel(
    const u32* __restrict__ mask, const float* __restrict__ s1,
    const float* __restrict__ s2, u16* __restrict__ att, int n)
{
    __shared__ float red[4];
    int i = blockIdx.x, tid = threadIdx.x;
    float s1i = s1[i];
    int j0 = tid * 16;
    u32 w = mask[(size_t)i * (n >> 5) + (j0 >> 5)];
    u32 bits = (j0 & 16) ? (w >> 16) : (w & 0xFFFFu);

    float e[16];
    float mx = -3.0e38f;
#pragma unroll
    for (int t = 0; t < 16; t++) {
        float x = s1i + s2[j0 + t];
        x = x > 0.f ? x : 0.2f * x;
        e[t] = x;
        if ((bits >> t) & 1u) mx = fmaxf(mx, x);
    }
    mx = block_max4(mx, red);

    float sum = 0.f;
#pragma unroll
    for (int t = 0; t < 16; t++) {
        float pv = ((bits >> t) & 1u) ? expf(e[t] - mx) : 0.f;
        e[t] = pv;
        sum += pv;
    }
    sum = block_sum4(sum, red);
    float rinv = sum > 0.f ? 1.f / sum : 0.f;
#pragma unroll
    for (int t = 0; t < 16; t++)
        att[(size_t)i * n + j0 + t] = f2bf(e[t] * rinv);
}

// --------------------------------------------------------------- fuse ----
__global__ __launch_bounds__(64) void fuse_kernel(
    const u16* __restrict__ E1, const u16* __restrict__ E2,
    const float* __restrict__ W, const float* __restrict__ U,
    float* __restrict__ fused, float* __restrict__ alpha)
{
    __shared__ float e1[64], e2[64];
    int i = blockIdx.x, d = threadIdx.x;
    e1[d] = bf2f(E1[i * 64 + d]);
    e2[d] = bf2f(E2[i * 64 + d]);
    __syncthreads();
    float v1 = 0.f, v2 = 0.f;
#pragma unroll 8
    for (int f = 0; f < 64; f++) {
        float w = W[f * 64 + d];
        v1 += e1[f] * w;
        v2 += e2[f] * w;
    }
    v1 = tanhf(v1); v2 = tanhf(v2);
    float u = U[d];
    float p1 = v1 * u, p2 = v2 * u;
#pragma unroll
    for (int off = 32; off; off >>= 1) {
        p1 += __shfl_down(p1, off);
        p2 += __shfl_down(p2, off);
    }
    p1 = __shfl(p1, 0); p2 = __shfl(p2, 0);
    float m = fmaxf(p1, p2);
    float w1 = expf(p1 - m), w2 = expf(p2 - m);
    float a1 = w1 / (w1 + w2), a2 = w2 / (w1 + w2);
    fused[i * 64 + d] = a1 * e1[d] + a2 * e2[d];
    if (alpha != nullptr && d < 2) alpha[i * 2 + d] = (d == 0 ? a1 : a2);
}

// ------------------------------------------------------------- bitpack ----
__global__ void bitpack_kernel(const int* __restrict__ adj,
                               u32* __restrict__ mask, int nwords)
{
    int w = blockIdx.x * 256 + threadIdx.x;
    if (w >= nwords) return;
    const int* src = adj + (size_t)w * 32;
    u32 m = 0;
#pragma unroll
    for (int b = 0; b < 32; b++) m |= (src[b] > 0 ? 1u : 0u) << b;
    mask[w] = m;
}

// ------------------------------------------------------------- driver ----
extern "C" void kernel_launch(void* const* d_in, const int* in_sizes, int n_in,
                              void* d_out, int out_size, void* d_ws, size_t ws_size,
                              hipStream_t stream)
{
    const int N = 4096, DIN = 3000, DH = 512, DO = 64;
    const float* x      = (const float*)d_in[0];
    const int*   adjF   = (const int*)d_in[1];
    const int*   adjS   = (const int*)d_in[2];
    const float* We1    = (const float*)d_in[3];
    const float* aE1    = (const float*)d_in[4];
    const float* We2    = (const float*)d_in[5];
    const float* aE2    = (const float*)d_in[6];
    const float* Wd1    = (const float*)d_in[7];
    const float* aD1    = (const float*)d_in[8];
    const float* Wd2    = (const float*)d_in[9];
    const float* aD2    = (const float*)d_in[10];
    const float* Womega = (const float*)d_in[11];
    const float* Uomega = (const float*)d_in[12];

    float* out       = (float*)d_out;
    float* out_emb   = out;                          // [4096,64]
    float* out_recon = out + (size_t)N * DO;         // [4096,3000]
    float* out_corr  = out_recon + (size_t)N * DIN;  // [4096,64]
    float* out_alpha = out_corr + (size_t)N * DO;    // [4096,2]

    char* ws = (char*)d_ws;
    size_t off = 0;
    auto alloc = [&](size_t bytes) {
        size_t o = off; off += (bytes + 255) & ~(size_t)255; return o;
    };
    const size_t o_att   = alloc((size_t)N * N * 2);        // 33.6 MB
    const size_t o_maskF = alloc((size_t)N * (N / 32) * 4); // 2.1 MB
    const size_t o_maskS = alloc((size_t)N * (N / 32) * 4);
    const size_t o_s1    = alloc((size_t)N * 4);
    const size_t o_s2    = alloc((size_t)N * 4);
    const size_t o_wh1   = alloc((size_t)N * DH * 2);       // wh1x / whc1
    const size_t o_h1a   = alloc((size_t)N * DH * 2);       // h1f / c1f
    const size_t o_h1b   = alloc((size_t)N * DH * 2);       // h1s / c1s
    const size_t o_whd1  = alloc((size_t)N * DH * 2);
    const size_t o_d1    = alloc((size_t)N * DH * 2);
    const size_t o_whd2  = alloc((size_t)N * DIN * 2);      // 24.6 MB
    size_t o_b64[8];
    for (int i = 0; i < 8; i++) o_b64[i] = alloc((size_t)N * DO * 2);

    u16* att    = (u16*)(ws + o_att);
    u32* maskF  = (u32*)(ws + o_maskF);
    u32* maskS  = (u32*)(ws + o_maskS);
    float* s1   = (float*)(ws + o_s1);
    float* s2   = (float*)(ws + o_s2);
    u16* wh1x   = (u16*)(ws + o_wh1);
    u16* whc1   = (u16*)(ws + o_wh1);
    u16* h1f    = (u16*)(ws + o_h1a);
    u16* c1f    = (u16*)(ws + o_h1a);
    u16* h1s    = (u16*)(ws + o_h1b);
    u16* c1s    = (u16*)(ws + o_h1b);
    u16* whd1   = (u16*)(ws + o_whd1);
    u16* d1b    = (u16*)(ws + o_d1);
    u16* whd2   = (u16*)(ws + o_whd2);
    u16* wh2f   = (u16*)(ws + o_b64[0]);
    u16* wh2s   = (u16*)(ws + o_b64[1]);
    u16* h2f    = (u16*)(ws + o_b64[2]);
    u16* h2s    = (u16*)(ws + o_b64[3]);
    u16* whc2f  = (u16*)(ws + o_b64[4]);
    u16* whc2s  = (u16*)(ws + o_b64[5]);
    u16* c2f    = (u16*)(ws + o_b64[6]);
    u16* c2s    = (u16*)(ws + o_b64[7]);

    auto grid = [](int M, int Nn) { return dim3((Nn + 63) / 64, (M + 127) / 128); };
    // A f32 split, B f32 split (near-f32 precision) -> bf16 internal
    auto gemm_ff = [&](const float* A, const float* B, u16* C, int M, int Nn, int K) {
        mgemm<2, 2, false, false><<<grid(M, Nn), 256, 0, stream>>>(A, B, C, M, Nn, K);
    };
    // A internal bf16, B f32 weight split -> bf16 internal
    auto gemm_hw = [&](const u16* A, const float* B, u16* C, int M, int Nn, int K) {
        mgemm<0, 2, false, false><<<grid(M, Nn), 256, 0, stream>>>(A, B, C, M, Nn, K);
    };
    // att(bf16) @ Wh(bf16), ELU -> bf16 internal
    auto gemm_att = [&](const u16* A, const u16* B, u16* C, int M, int Nn, int K) {
        mgemm<0, 0, true, false><<<grid(M, Nn), 256, 0, stream>>>(A, B, C, M, Nn, K);
    };
    // att(bf16) @ Wh(bf16), ELU -> f32 (recon into d_out)
    auto gemm_att_f32 = [&](const u16* A, const u16* B, float* C, int M, int Nn, int K) {
        mgemm<0, 0, true, true><<<grid(M, Nn), 256, 0, stream>>>(A, B, C, M, Nn, K);
    };
    auto scores = [&](const u16* Wh, int ld, int F, const float* a) {
        scores_kernel<<<N, 256, 0, stream>>>(Wh, ld, F, a, s1, s2);
    };
    auto attb = [&](const u32* mask) {
        att_kernel<<<N, 256, 0, stream>>>(mask, s1, s2, att, N);
    };

    // ---- prep: bitmasks ----
    bitpack_kernel<<<(N * (N / 32) + 255) / 256, 256, 0, stream>>>(adjF, maskF, N * (N / 32));
    bitpack_kernel<<<(N * (N / 32) + 255) / 256, 256, 0, stream>>>(adjS, maskS, N * (N / 32));

    // ---- encoder layer 1 (Wh shared across both adjacencies) ----
    gemm_ff(x, We1, wh1x, N, DH, DIN);
    scores(wh1x, DH, DH, aE1);
    attb(maskF); gemm_att(att, wh1x, h1f, N, DH, N);
    attb(maskS); gemm_att(att, wh1x, h1s, N, DH, N);

    // ---- encoder layer 2 ----
    gemm_hw(h1f, We2, wh2f, N, DO, DH);
    scores(wh2f, DO, DO, aE2);
    attb(maskF); gemm_att(att, wh2f, h2f, N, DO, N);
    gemm_hw(h1s, We2, wh2s, N, DO, DH);
    scores(wh2s, DO, DO, aE2);
    attb(maskS); gemm_att(att, wh2s, h2s, N, DO, N);

    // ---- fuse -> emb_latent (f32 in d_out) + alpha ----
    fuse_kernel<<<N, 64, 0, stream>>>(h2f, h2s, Womega, Uomega, out_emb, out_alpha);

    // ---- decoder layer 1 (spatial adj); A = out_emb (f32) ----
    mgemm<2, 2, false, false><<<grid(N, DH), 256, 0, stream>>>(
        out_emb, Wd1, whd1, N, DH, DO);
    scores(whd1, DH, DH, aD1);
    attb(maskS); gemm_att(att, whd1, d1b, N, DH, N);

    // ---- decoder layer 2 (spatial adj); recon (f32) into d_out ----
    gemm_hw(d1b, Wd2, whd2, N, DIN, DH);
    scores(whd2, DIN, DIN, aD2);
    attb(maskS); gemm_att_f32(att, whd2, out_recon, N, DIN, N);

    // ---- corr encoder layer 1 (A = recon f32 from d_out) ----
    gemm_ff(out_recon, We1, whc1, N, DH, DIN);
    scores(whc1, DH, DH, aE1);
    attb(maskF); gemm_att(att, whc1, c1f, N, DH, N);
    attb(maskS); gemm_att(att, whc1, c1s, N, DH, N);

    // ---- corr encoder layer 2 ----
    gemm_hw(c1f, We2, whc2f, N, DO, DH);
    scores(whc2f, DO, DO, aE2);
    attb(maskF); gemm_att(att, whc2f, c2f, N, DO, N);
    gemm_hw(c1s, We2, whc2s, N, DO, DH);
    scores(whc2s, DO, DO, aE2);
    attb(maskS); gemm_att(att, whc2s, c2s, N, DO, N);

    // ---- fuse -> corr (f32 in d_out) ----
    fuse_kernel<<<N, 64, 0, stream>>>(c2f, c2s, Womega, Uomega, out_corr, nullptr);
}

// Round 4
// 1873.254 us; speedup vs baseline: 5.9753x; 1.8225x over previous
//
#include <hip/hip_runtime.h>
#include <hip/hip_bf16.h>
#include <math.h>

using u16 = unsigned short;
using u32 = unsigned int;

typedef __attribute__((ext_vector_type(8))) short s8v;    // 8 x bf16 bits (4 VGPRs)
typedef __attribute__((ext_vector_type(4))) float f4v;    // MFMA acc

__device__ __forceinline__ float bf2f(u16 u) {
    u32 x = ((u32)u) << 16;
    return __builtin_bit_cast(float, x);
}
__device__ __forceinline__ u16 f2bf(float f) {
    u32 x = __builtin_bit_cast(u32, f);
    x += 0x7fffu + ((x >> 16) & 1u);
    return (u16)(x >> 16);
}

__device__ __forceinline__ f4v mfma_bf16(s8v a, s8v b, f4v c) {
    return __builtin_amdgcn_mfma_f32_16x16x32_bf16(a, b, c, 0, 0, 0);
}

// ------------------------------------------------------------- tgemm ----
// Fast path for the att-GEMMs: C[M,N] = A[M,K] @ B[K,N], where A is bf16
// row-major [M,K] and B is supplied TRANSPOSED as Bt[N,K] bf16 row-major
// (k-contiguous). Staging via global_load_lds width=16 into linear LDS with
// XOR chunk swizzle (chunk ^= row&7; swizzle applied on the per-lane GLOBAL
// source address, LDS dest stays linear; reads apply the same XOR).
// Requires M%128==0, K%64==0 (true for all uses: M=K=4096). N arbitrary
// (B rows clamped, epilogue bounds-checked).
// BM=128, BN=64, BK=64; 256 thr = 4 waves (2x2); wave tile 64x32; acc 4x2.
template<bool DO_ELU, bool OUT_F32>
__global__ __launch_bounds__(256) void tgemm(
    const u16* __restrict__ A, const u16* __restrict__ Bt,
    void* __restrict__ Cv, int M, int N, int K)
{
    constexpr int BM = 128, BN = 64, BK = 64;
    // linear LDS: row stride = 64 u16 = 128B = 8 chunks of 16B
    __shared__ __align__(16) u16 As[BM * BK];   // 16 KB
    __shared__ __align__(16) u16 Bs[BN * BK];   // 8 KB

    const int bm0 = blockIdx.y * BM, bn0 = blockIdx.x * BN;
    const int tid = threadIdx.x;
    const int lane = tid & 63;
    const int wave = tid >> 6;
    const int wr = wave >> 1;        // wave row (64 rows)
    const int wc = wave & 1;         // wave col (32 cols)
    const int lr = lane & 15;
    const int srow = lane >> 3;      // staging: row within 8-row group
    const int schk = lane & 7;       // staging: dest chunk index

    f4v acc[4][2] = {};

    for (int k0 = 0; k0 < K; k0 += BK) {
        // ---- stage A: 16 x 1KB wave-chunks; wave w does 4 ----
#pragma unroll
        for (int ci = 0; ci < 4; ci++) {
            const int r8 = (wave * 4 + ci) * 8;
            const int row = r8 + srow;
            const int gchk = schk ^ (row & 7);   // inverse-swizzled source
            const u16* src = A + (size_t)(bm0 + row) * K + k0 + gchk * 8;
            __builtin_amdgcn_global_load_lds(
                (const __attribute__((address_space(1))) void*)src,
                (__attribute__((address_space(3))) void*)&As[r8 * 64],
                16, 0, 0);
        }
        // ---- stage B^T: 8 x 1KB wave-chunks; wave w does 2 ----
#pragma unroll
        for (int ci = 0; ci < 2; ci++) {
            const int r8 = (wave * 2 + ci) * 8;
            const int row = r8 + srow;
            int gn = bn0 + row;
            if (gn >= N) gn = N - 1;             // clamp (epilogue masks)
            const int gchk = schk ^ (row & 7);
            const u16* src = Bt + (size_t)gn * K + k0 + gchk * 8;
            __builtin_amdgcn_global_load_lds(
                (const __attribute__((address_space(1))) void*)src,
                (__attribute__((address_space(3))) void*)&Bs[r8 * 64],
                16, 0, 0);
        }
        __syncthreads();   // compiler drains vmcnt before barrier

        // ---- fragments + MFMA: k-slices kk=0,32 ----
#pragma unroll
        for (int kk = 0; kk < 2; kk++) {
            const int cbase = (lane >> 4) + kk * 4;  // chunk of this lane's 8 elems
            s8v a[4], b[2];
#pragma unroll
            for (int m = 0; m < 4; m++) {
                const int row = wr * 64 + m * 16 + lr;
                const int chk = cbase ^ (row & 7);
                a[m] = *(const s8v*)&As[row * 64 + chk * 8];
            }
#pragma unroll
            for (int n = 0; n < 2; n++) {
                const int row = wc * 32 + n * 16 + lr;
                const int chk = cbase ^ (row & 7);
                b[n] = *(const s8v*)&Bs[row * 64 + chk * 8];
            }
#pragma unroll
            for (int m = 0; m < 4; m++)
#pragma unroll
                for (int n = 0; n < 2; n++)
                    acc[m][n] = mfma_bf16(a[m], b[n], acc[m][n]);
        }
        __syncthreads();
    }

    // ---- epilogue: D row = 4*(lane>>4)+i, col = lane&15 ----
#pragma unroll
    for (int m = 0; m < 4; m++)
#pragma unroll
        for (int n = 0; n < 2; n++)
#pragma unroll
            for (int i = 0; i < 4; i++) {
                int gm = bm0 + wr * 64 + m * 16 + (lane >> 4) * 4 + i;
                int gn = bn0 + wc * 32 + n * 16 + lr;
                if (gm < M && gn < N) {
                    float val = acc[m][n][i];
                    if (DO_ELU) val = val > 0.f ? val : expm1f(val);
                    if (OUT_F32) ((float*)Cv)[(size_t)gm * N + gn] = val;
                    else         ((u16*)Cv)[(size_t)gm * N + gn] = f2bf(val);
                }
            }
}

// ---------------------------------------------------------- transpose ----
// dst[C][R] = src[R][C], bf16. 32x32 LDS tiles, 256 threads.
__global__ __launch_bounds__(256) void tr_kernel(
    const u16* __restrict__ src, u16* __restrict__ dst, int R, int C)
{
    __shared__ u16 t[32][33];
    const int r0 = blockIdx.y * 32, c0 = blockIdx.x * 32;
    const int tr = threadIdx.x >> 5, tc = threadIdx.x & 31;
#pragma unroll
    for (int i = 0; i < 4; i++) {
        int r = r0 + tr + i * 8, c = c0 + tc;
        t[tr + i * 8][tc] = (r < R && c < C) ? src[(size_t)r * C + c] : (u16)0;
    }
    __syncthreads();
#pragma unroll
    for (int i = 0; i < 4; i++) {
        int c = c0 + tr + i * 8, r = r0 + tc;
        if (c < C && r < R) dst[(size_t)c * R + r] = t[tc][tr + i * 8];
    }
}

// ---------------------------------------------------------------- GEMM ----
// Reg-staged path for weight GEMMs (f32 operands, bf16 hi+lo split).
// C[M,N] = A[M,K] @ B[K,N]. AMODE/BMODE: 0 = bf16 in memory, 2 = f32 split.
template<int AMODE, int BMODE, bool DO_ELU, bool OUT_F32>
__global__ __launch_bounds__(256) void mgemm(
    const void* __restrict__ Av, const void* __restrict__ Bv,
    void* __restrict__ Cv, int M, int N, int K)
{
    constexpr int BM = 128, BN = 64, BK = 32;
    constexpr int KP = BK + 8;
    constexpr bool ASP = (AMODE == 2);
    constexpr bool BSP = (BMODE == 2);
    constexpr int NA = ASP ? 2 : 1;
    constexpr int NB = BSP ? 2 : 1;

    __shared__ __align__(16) u16 As[NA][BM][KP];
    __shared__ __align__(16) u16 Bs[NB][BN][KP];

    const int bm0 = blockIdx.y * BM, bn0 = blockIdx.x * BN;
    const int tid = threadIdx.x;
    const int lane = tid & 63;
    const int wave = tid >> 6;
    const int wr = wave >> 1;
    const int wc = wave & 1;
    const int lr = lane & 15;
    const int kb = (lane >> 4) * 8;

    f4v acc[4][2] = {};

    for (int k0 = 0; k0 < K; k0 += BK) {
        for (int u = tid; u < BM * (BK / 8); u += 256) {
            const int row = u >> 2;
            const int ks = (u & 3) * 8;
            const int gm = bm0 + row, gk = k0 + ks;
            if constexpr (AMODE == 0) {
                const u16* Ab = (const u16*)Av;
                s8v v = {};
                if (gm < M) {
                    if (gk + 8 <= K) {
                        v = *(const s8v*)(Ab + (size_t)gm * K + gk);
                    } else if (gk < K) {
#pragma unroll
                        for (int j = 0; j < 8; j++)
                            ((u16*)&v)[j] = (gk + j < K) ? Ab[(size_t)gm * K + gk + j] : (u16)0;
                    }
                }
                *(s8v*)&As[0][row][ks] = v;
            } else {
                const float* Af = (const float*)Av;
                float v[8] = {0.f,0.f,0.f,0.f,0.f,0.f,0.f,0.f};
                if (gm < M) {
                    if (gk + 8 <= K) {
                        const float4* p = (const float4*)(Af + (size_t)gm * K + gk);
                        float4 x0 = p[0], x1 = p[1];
                        v[0]=x0.x; v[1]=x0.y; v[2]=x0.z; v[3]=x0.w;
                        v[4]=x1.x; v[5]=x1.y; v[6]=x1.z; v[7]=x1.w;
                    } else if (gk < K) {
#pragma unroll
                        for (int j = 0; j < 8; j++)
                            if (gk + j < K) v[j] = Af[(size_t)gm * K + gk + j];
                    }
                }
                s8v hi, lo;
#pragma unroll
                for (int j = 0; j < 8; j++) {
                    u16 h = f2bf(v[j]);
                    ((u16*)&hi)[j] = h;
                    ((u16*)&lo)[j] = f2bf(v[j] - bf2f(h));
                }
                *(s8v*)&As[0][row][ks] = hi;
                *(s8v*)&As[1][row][ks] = lo;
            }
        }
        {
            const int k = tid >> 3;
            const int p = tid & 7;
            const int n0 = p * 8;
            const int gk = k0 + k;
            if constexpr (BMODE == 0) {
                const u16* Bb = (const u16*)Bv;
                s8v v = {};
                if (gk < K) {
                    if (bn0 + n0 + 8 <= N) {
                        v = *(const s8v*)(Bb + (size_t)gk * N + bn0 + n0);
                    } else {
#pragma unroll
                        for (int j = 0; j < 8; j++)
                            ((u16*)&v)[j] = (bn0 + n0 + j < N) ? Bb[(size_t)gk * N + bn0 + n0 + j] : (u16)0;
                    }
                }
#pragma unroll
                for (int jj = 0; jj < 8; jj++) {
                    int j = (jj + p) & 7;
                    Bs[0][n0 + j][k] = ((u16*)&v)[j];
                }
            } else {
                const float* Bf = (const float*)Bv;
                float v[8] = {0.f,0.f,0.f,0.f,0.f,0.f,0.f,0.f};
                if (gk < K) {
                    if (bn0 + n0 + 8 <= N) {
                        const float4* pp = (const float4*)(Bf + (size_t)gk * N + bn0 + n0);
                        float4 x0 = pp[0], x1 = pp[1];
                        v[0]=x0.x; v[1]=x0.y; v[2]=x0.z; v[3]=x0.w;
                        v[4]=x1.x; v[5]=x1.y; v[6]=x1.z; v[7]=x1.w;
                    } else {
#pragma unroll
                        for (int j = 0; j < 8; j++)
                            if (bn0 + n0 + j < N) v[j] = Bf[(size_t)gk * N + bn0 + n0 + j];
                    }
                }
#pragma unroll
                for (int jj = 0; jj < 8; jj++) {
                    int j = (jj + p) & 7;
                    u16 h = f2bf(v[j]);
                    Bs[0][n0 + j][k] = h;
                    Bs[1][n0 + j][k] = f2bf(v[j] - bf2f(h));
                }
            }
        }
        __syncthreads();

        s8v a0[4], a1[ASP ? 4 : 1];
        s8v b0[2], b1[BSP ? 2 : 1];
#pragma unroll
        for (int m = 0; m < 4; m++) {
            a0[m] = *(const s8v*)&As[0][wr * 64 + m * 16 + lr][kb];
            if constexpr (ASP) a1[m] = *(const s8v*)&As[1][wr * 64 + m * 16 + lr][kb];
        }
#pragma unroll
        for (int n = 0; n < 2; n++) {
            b0[n] = *(const s8v*)&Bs[0][wc * 32 + n * 16 + lr][kb];
            if constexpr (BSP) b1[n] = *(const s8v*)&Bs[1][wc * 32 + n * 16 + lr][kb];
        }
#pragma unroll
        for (int m = 0; m < 4; m++)
#pragma unroll
            for (int n = 0; n < 2; n++) {
                acc[m][n] = mfma_bf16(a0[m], b0[n], acc[m][n]);
                if constexpr (ASP) acc[m][n] = mfma_bf16(a1[m], b0[n], acc[m][n]);
                if constexpr (BSP) acc[m][n] = mfma_bf16(a0[m], b1[n], acc[m][n]);
            }
        __syncthreads();
    }

#pragma unroll
    for (int m = 0; m < 4; m++)
#pragma unroll
        for (int n = 0; n < 2; n++)
#pragma unroll
            for (int i = 0; i < 4; i++) {
                int gm = bm0 + wr * 64 + m * 16 + (lane >> 4) * 4 + i;
                int gn = bn0 + wc * 32 + n * 16 + lr;
                if (gm < M && gn < N) {
                    float val = acc[m][n][i];
                    if (DO_ELU) val = val > 0.f ? val : expm1f(val);
                    if (OUT_F32) ((float*)Cv)[(size_t)gm * N + gn] = val;
                    else         ((u16*)Cv)[(size_t)gm * N + gn] = f2bf(val);
                }
            }
}

// ------------------------------------------------------------- reduce ----
__device__ __forceinline__ float block_sum4(float v, float* red) {
#pragma unroll
    for (int off = 32; off; off >>= 1) v += __shfl_down(v, off);
    int w = threadIdx.x >> 6;
    if ((threadIdx.x & 63) == 0) red[w] = v;
    __syncthreads();
    float r = red[0] + red[1] + red[2] + red[3];
    __syncthreads();
    return r;
}
__device__ __forceinline__ float block_max4(float v, float* red) {
#pragma unroll
    for (int off = 32; off; off >>= 1) v = fmaxf(v, __shfl_down(v, off));
    int w = threadIdx.x >> 6;
    if ((threadIdx.x & 63) == 0) red[w] = v;
    __syncthreads();
    float r = fmaxf(fmaxf(red[0], red[1]), fmaxf(red[2], red[3]));
    __syncthreads();
    return r;
}

// ------------------------------------------------------------- scores ----
__global__ __launch_bounds__(256) void scores_kernel(
    const u16* __restrict__ Wh, int ld, int F, const float* __restrict__ a,
    float* __restrict__ s1, float* __restrict__ s2)
{
    __shared__ float red[4];
    int i = blockIdx.x, tid = threadIdx.x;
    float acc1 = 0.f, acc2 = 0.f;
    for (int f = tid; f < F; f += 256) {
        float w = bf2f(Wh[(size_t)i * ld + f]);
        acc1 += w * a[f];
        acc2 += w * a[F + f];
    }
    acc1 = block_sum4(acc1, red);
    acc2 = block_sum4(acc2, red);
    if (tid == 0) { s1[i] = acc1; s2[i] = acc2; }
}

// ---------------------------------------------------------------- att ----
__global__ __launch_bounds__(256) void att_kernel(
    const u32* __restrict__ mask, const float* __restrict__ s1,
    const float* __restrict__ s2, u16* __restrict__ att, int n)
{
    __shared__ float red[4];
    int i = blockIdx.x, tid = threadIdx.x;
    float s1i = s1[i];
    int j0 = tid * 16;
    u32 w = mask[(size_t)i * (n >> 5) + (j0 >> 5)];
    u32 bits = (j0 & 16) ? (w >> 16) : (w & 0xFFFFu);

    float e[16];
    float mx = -3.0e38f;
#pragma unroll
    for (int t = 0; t < 16; t++) {
        float x = s1i + s2[j0 + t];
        x = x > 0.f ? x : 0.2f * x;
        e[t] = x;
        if ((bits >> t) & 1u) mx = fmaxf(mx, x);
    }
    mx = block_max4(mx, red);

    float sum = 0.f;
#pragma unroll
    for (int t = 0; t < 16; t++) {
        float pv = ((bits >> t) & 1u) ? expf(e[t] - mx) : 0.f;
        e[t] = pv;
        sum += pv;
    }
    sum = block_sum4(sum, red);
    float rinv = sum > 0.f ? 1.f / sum : 0.f;
#pragma unroll
    for (int t = 0; t < 16; t++)
        att[(size_t)i * n + j0 + t] = f2bf(e[t] * rinv);
}

// --------------------------------------------------------------- fuse ----
__global__ __launch_bounds__(64) void fuse_kernel(
    const u16* __restrict__ E1, const u16* __restrict__ E2,
    const float* __restrict__ W, const float* __restrict__ U,
    float* __restrict__ fused, float* __restrict__ alpha)
{
    __shared__ float e1[64], e2[64];
    int i = blockIdx.x, d = threadIdx.x;
    e1[d] = bf2f(E1[i * 64 + d]);
    e2[d] = bf2f(E2[i * 64 + d]);
    __syncthreads();
    float v1 = 0.f, v2 = 0.f;
#pragma unroll 8
    for (int f = 0; f < 64; f++) {
        float w = W[f * 64 + d];
        v1 += e1[f] * w;
        v2 += e2[f] * w;
    }
    v1 = tanhf(v1); v2 = tanhf(v2);
    float u = U[d];
    float p1 = v1 * u, p2 = v2 * u;
#pragma unroll
    for (int off = 32; off; off >>= 1) {
        p1 += __shfl_down(p1, off);
        p2 += __shfl_down(p2, off);
    }
    p1 = __shfl(p1, 0); p2 = __shfl(p2, 0);
    float m = fmaxf(p1, p2);
    float w1 = expf(p1 - m), w2 = expf(p2 - m);
    float a1 = w1 / (w1 + w2), a2 = w2 / (w1 + w2);
    fused[i * 64 + d] = a1 * e1[d] + a2 * e2[d];
    if (alpha != nullptr && d < 2) alpha[i * 2 + d] = (d == 0 ? a1 : a2);
}

// ------------------------------------------------------------- bitpack ----
__global__ void bitpack_kernel(const int* __restrict__ adj,
                               u32* __restrict__ mask, int nwords)
{
    int w = blockIdx.x * 256 + threadIdx.x;
    if (w >= nwords) return;
    const int* src = adj + (size_t)w * 32;
    u32 m = 0;
#pragma unroll
    for (int b = 0; b < 32; b++) m |= (src[b] > 0 ? 1u : 0u) << b;
    mask[w] = m;
}

// ------------------------------------------------------------- driver ----
extern "C" void kernel_launch(void* const* d_in, const int* in_sizes, int n_in,
                              void* d_out, int out_size, void* d_ws, size_t ws_size,
                              hipStream_t stream)
{
    const int N = 4096, DIN = 3000, DH = 512, DO = 64;
    const float* x      = (const float*)d_in[0];
    const int*   adjF   = (const int*)d_in[1];
    const int*   adjS   = (const int*)d_in[2];
    const float* We1    = (const float*)d_in[3];
    const float* aE1    = (const float*)d_in[4];
    const float* We2    = (const float*)d_in[5];
    const float* aE2    = (const float*)d_in[6];
    const float* Wd1    = (const float*)d_in[7];
    const float* aD1    = (const float*)d_in[8];
    const float* Wd2    = (const float*)d_in[9];
    const float* aD2    = (const float*)d_in[10];
    const float* Womega = (const float*)d_in[11];
    const float* Uomega = (const float*)d_in[12];

    float* out       = (float*)d_out;
    float* out_emb   = out;                          // [4096,64]
    float* out_recon = out + (size_t)N * DO;         // [4096,3000]
    float* out_corr  = out_recon + (size_t)N * DIN;  // [4096,64]
    float* out_alpha = out_corr + (size_t)N * DO;    // [4096,2]

    char* ws = (char*)d_ws;
    size_t off = 0;
    auto alloc = [&](size_t bytes) {
        size_t o = off; off += (bytes + 255) & ~(size_t)255; return o;
    };
    const size_t o_att   = alloc((size_t)N * N * 2);        // 33.6 MB
    const size_t o_maskF = alloc((size_t)N * (N / 32) * 4);
    const size_t o_maskS = alloc((size_t)N * (N / 32) * 4);
    const size_t o_s1    = alloc((size_t)N * 4);
    const size_t o_s2    = alloc((size_t)N * 4);
    const size_t o_wh1   = alloc((size_t)N * DH * 2);       // wh1x / whc1
    const size_t o_h1a   = alloc((size_t)N * DH * 2);       // h1f / c1f
    const size_t o_h1b   = alloc((size_t)N * DH * 2);       // h1s / c1s
    const size_t o_whd1  = alloc((size_t)N * DH * 2);
    const size_t o_d1    = alloc((size_t)N * DH * 2);
    const size_t o_whd2  = alloc((size_t)N * DIN * 2);      // 24.6 MB
    size_t o_b64[8];
    for (int i = 0; i < 8; i++) o_b64[i] = alloc((size_t)N * DO * 2);
    // transposed-B buffers for tgemm
    const size_t o_t512  = alloc((size_t)DH * N * 2);       // wh1x_t / whc1_t (shared)
    const size_t o_td1   = alloc((size_t)DH * N * 2);       // whd1_t
    const size_t o_td2   = alloc((size_t)DIN * N * 2);      // whd2_t, 24.6 MB
    const size_t o_t64a  = alloc((size_t)DO * N * 2);       // wh2f_t / whc2f_t
    const size_t o_t64b  = alloc((size_t)DO * N * 2);       // wh2s_t / whc2s_t

    u16* att    = (u16*)(ws + o_att);
    u32* maskF  = (u32*)(ws + o_maskF);
    u32* maskS  = (u32*)(ws + o_maskS);
    float* s1   = (float*)(ws + o_s1);
    float* s2   = (float*)(ws + o_s2);
    u16* wh1x   = (u16*)(ws + o_wh1);
    u16* whc1   = (u16*)(ws + o_wh1);
    u16* h1f    = (u16*)(ws + o_h1a);
    u16* c1f    = (u16*)(ws + o_h1a);
    u16* h1s    = (u16*)(ws + o_h1b);
    u16* c1s    = (u16*)(ws + o_h1b);
    u16* whd1   = (u16*)(ws + o_whd1);
    u16* d1b    = (u16*)(ws + o_d1);
    u16* whd2   = (u16*)(ws + o_whd2);
    u16* wh2f   = (u16*)(ws + o_b64[0]);
    u16* wh2s   = (u16*)(ws + o_b64[1]);
    u16* h2f    = (u16*)(ws + o_b64[2]);
    u16* h2s    = (u16*)(ws + o_b64[3]);
    u16* whc2f  = (u16*)(ws + o_b64[4]);
    u16* whc2s  = (u16*)(ws + o_b64[5]);
    u16* c2f    = (u16*)(ws + o_b64[6]);
    u16* c2s    = (u16*)(ws + o_b64[7]);
    u16* t512   = (u16*)(ws + o_t512);
    u16* td1    = (u16*)(ws + o_td1);
    u16* td2    = (u16*)(ws + o_td2);
    u16* t64a   = (u16*)(ws + o_t64a);
    u16* t64b   = (u16*)(ws + o_t64b);

    auto grid = [](int M, int Nn) { return dim3((Nn + 63) / 64, (M + 127) / 128); };
    auto gemm_ff = [&](const float* A, const float* B, u16* C, int M, int Nn, int K) {
        mgemm<2, 2, false, false><<<grid(M, Nn), 256, 0, stream>>>(A, B, C, M, Nn, K);
    };
    auto gemm_hw = [&](const u16* A, const float* B, u16* C, int M, int Nn, int K) {
        mgemm<0, 2, false, false><<<grid(M, Nn), 256, 0, stream>>>(A, B, C, M, Nn, K);
    };
    // fast att-GEMM: att(bf16) @ Wh(via Wh^T), ELU epilogue
    auto gatt = [&](const u16* Bt, u16* C, int Nn) {
        tgemm<true, false><<<grid(N, Nn), 256, 0, stream>>>(att, Bt, C, N, Nn, N);
    };
    auto gatt_f32 = [&](const u16* Bt, float* C, int Nn) {
        tgemm<true, true><<<grid(N, Nn), 256, 0, stream>>>(att, Bt, C, N, Nn, N);
    };
    auto tr = [&](const u16* src, u16* dst, int R, int C) {
        tr_kernel<<<dim3((C + 31) / 32, (R + 31) / 32), 256, 0, stream>>>(src, dst, R, C);
    };
    auto scores = [&](const u16* Wh, int ld, int F, const float* a) {
        scores_kernel<<<N, 256, 0, stream>>>(Wh, ld, F, a, s1, s2);
    };
    auto attb = [&](const u32* mask) {
        att_kernel<<<N, 256, 0, stream>>>(mask, s1, s2, att, N);
    };

    // ---- prep: bitmasks ----
    bitpack_kernel<<<(N * (N / 32) + 255) / 256, 256, 0, stream>>>(adjF, maskF, N * (N / 32));
    bitpack_kernel<<<(N * (N / 32) + 255) / 256, 256, 0, stream>>>(adjS, maskS, N * (N / 32));

    // ---- encoder layer 1 (Wh shared across both adjacencies) ----
    gemm_ff(x, We1, wh1x, N, DH, DIN);
    tr(wh1x, t512, N, DH);
    scores(wh1x, DH, DH, aE1);
    attb(maskF); gatt(t512, h1f, DH);
    attb(maskS); gatt(t512, h1s, DH);

    // ---- encoder layer 2 ----
    gemm_hw(h1f, We2, wh2f, N, DO, DH);
    tr(wh2f, t64a, N, DO);
    scores(wh2f, DO, DO, aE2);
    attb(maskF); gatt(t64a, h2f, DO);
    gemm_hw(h1s, We2, wh2s, N, DO, DH);
    tr(wh2s, t64b, N, DO);
    scores(wh2s, DO, DO, aE2);
    attb(maskS); gatt(t64b, h2s, DO);

    // ---- fuse -> emb_latent (f32 in d_out) + alpha ----
    fuse_kernel<<<N, 64, 0, stream>>>(h2f, h2s, Womega, Uomega, out_emb, out_alpha);

    // ---- decoder layer 1 (spatial adj); A = out_emb (f32) ----
    mgemm<2, 2, false, false><<<grid(N, DH), 256, 0, stream>>>(
        out_emb, Wd1, whd1, N, DH, DO);
    tr(whd1, td1, N, DH);
    scores(whd1, DH, DH, aD1);
    attb(maskS); gatt(td1, d1b, DH);

    // ---- decoder layer 2 (spatial adj); recon (f32) into d_out ----
    gemm_hw(d1b, Wd2, whd2, N, DIN, DH);
    tr(whd2, td2, N, DIN);
    scores(whd2, DIN, DIN, aD2);
    attb(maskS); gatt_f32(td2, out_recon, DIN);

    // ---- corr encoder layer 1 (A = recon f32 from d_out) ----
    gemm_ff(out_recon, We1, whc1, N, DH, DIN);
    tr(whc1, t512, N, DH);
    scores(whc1, DH, DH, aE1);
    attb(maskF); gatt(t512, c1f, DH);
    attb(maskS); gatt(t512, c1s, DH);

    // ---- corr encoder layer 2 ----
    gemm_hw(c1f, We2, whc2f, N, DO, DH);
    tr(whc2f, t64a, N, DO);
    scores(whc2f, DO, DO, aE2);
    attb(maskF); gatt(t64a, c2f, DO);
    gemm_hw(c1s, We2, whc2s, N, DO, DH);
    tr(whc2s, t64b, N, DO);
    scores(whc2s, DO, DO, aE2);
    attb(maskS); gatt(t64b, c2s, DO);

    // ---- fuse -> corr (f32 in d_out) ----
    fuse_kernel<<<N, 64, 0, stream>>>(c2f, c2s, Womega, Uomega, out_corr, nullptr);
}

// Round 5
// 1321.195 us; speedup vs baseline: 8.4721x; 1.4178x over previous
//
#include <hip/hip_runtime.h>
#include <hip/hip_bf16.h>
#include <math.h>

using u16 = unsigned short;
using u32 = unsigned int;

typedef __attribute__((ext_vector_type(8))) short s8v;    // 8 x bf16 bits (4 VGPRs)
typedef __attribute__((ext_vector_type(4))) float f4v;    // MFMA acc

__device__ __forceinline__ float bf2f(u16 u) {
    u32 x = ((u32)u) << 16;
    return __builtin_bit_cast(float, x);
}
__device__ __forceinline__ u16 f2bf(float f) {
    u32 x = __builtin_bit_cast(u32, f);
    x += 0x7fffu + ((x >> 16) & 1u);
    return (u16)(x >> 16);
}

__device__ __forceinline__ f4v mfma_bf16(s8v a, s8v b, f4v c) {
    return __builtin_amdgcn_mfma_f32_16x16x32_bf16(a, b, c, 0, 0, 0);
}

#define GLL(srcp, dstp) __builtin_amdgcn_global_load_lds( \
    (const __attribute__((address_space(1))) void*)(srcp), \
    (__attribute__((address_space(3))) void*)(dstp), 16, 0, 0)

// ------------------------------------------------------------- tgemm ----
// att-GEMM fast path: C[M,N] = A[M,K] @ B[K,N], A bf16 [M,K] row-major,
// B supplied transposed Bt[N,K] bf16. global_load_lds width=16, linear LDS
// with XOR chunk swizzle (LDS[row][c] = G[row][c ^ (row&7)], involution
// applied on the per-lane global source; reads re-apply the XOR).
// Requires M%128==0, K%64==0. N arbitrary (clamped stage, masked epilogue).
// BM=128, BN=64, BK=64; 256 thr = 4 waves (2x2); wave tile 64x32; acc 4x2.
template<bool DO_ELU, bool OUT_F32>
__global__ __launch_bounds__(256) void tgemm(
    const u16* __restrict__ A, const u16* __restrict__ Bt,
    void* __restrict__ Cv, int M, int N, int K)
{
    constexpr int BM = 128, BN = 64, BK = 64;
    __shared__ __align__(16) u16 As[BM * BK];   // 16 KB
    __shared__ __align__(16) u16 Bs[BN * BK];   // 8 KB

    const int bm0 = blockIdx.y * BM, bn0 = blockIdx.x * BN;
    const int tid = threadIdx.x;
    const int lane = tid & 63;
    const int wave = tid >> 6;
    const int wr = wave >> 1;
    const int wc = wave & 1;
    const int lr = lane & 15;
    const int srow = lane >> 3;
    const int schk = lane & 7;

    f4v acc[4][2] = {};

    for (int k0 = 0; k0 < K; k0 += BK) {
#pragma unroll
        for (int ci = 0; ci < 4; ci++) {
            const int r8 = (wave * 4 + ci) * 8;
            const int row = r8 + srow;
            const int gchk = schk ^ (row & 7);
            GLL(A + (size_t)(bm0 + row) * K + k0 + gchk * 8, &As[r8 * 64]);
        }
#pragma unroll
        for (int ci = 0; ci < 2; ci++) {
            const int r8 = (wave * 2 + ci) * 8;
            const int row = r8 + srow;
            int gn = bn0 + row;
            if (gn >= N) gn = N - 1;
            const int gchk = schk ^ (row & 7);
            GLL(Bt + (size_t)gn * K + k0 + gchk * 8, &Bs[r8 * 64]);
        }
        __syncthreads();

#pragma unroll
        for (int kk = 0; kk < 2; kk++) {
            const int cbase = (lane >> 4) + kk * 4;
            s8v a[4], b[2];
#pragma unroll
            for (int m = 0; m < 4; m++) {
                const int row = wr * 64 + m * 16 + lr;
                a[m] = *(const s8v*)&As[row * 64 + (cbase ^ (row & 7)) * 8];
            }
#pragma unroll
            for (int n = 0; n < 2; n++) {
                const int row = wc * 32 + n * 16 + lr;
                b[n] = *(const s8v*)&Bs[row * 64 + (cbase ^ (row & 7)) * 8];
            }
#pragma unroll
            for (int m = 0; m < 4; m++)
#pragma unroll
                for (int n = 0; n < 2; n++)
                    acc[m][n] = mfma_bf16(a[m], b[n], acc[m][n]);
        }
        __syncthreads();
    }

#pragma unroll
    for (int m = 0; m < 4; m++)
#pragma unroll
        for (int n = 0; n < 2; n++)
#pragma unroll
            for (int i = 0; i < 4; i++) {
                int gm = bm0 + wr * 64 + m * 16 + (lane >> 4) * 4 + i;
                int gn = bn0 + wc * 32 + n * 16 + lr;
                if (gm < M && gn < N) {
                    float val = acc[m][n][i];
                    if (DO_ELU) val = val > 0.f ? val : expm1f(val);
                    if (OUT_F32) ((float*)Cv)[(size_t)gm * N + gn] = val;
                    else         ((u16*)Cv)[(size_t)gm * N + gn] = f2bf(val);
                }
            }
}

// ---------------------------------------------------------- tgemm_sk ----
// Split-K variant for small-N att-GEMMs (N=64): grid.z slices K; f32
// partials P[z][M][N]; no epilogue (skred applies ELU + bf16).
__global__ __launch_bounds__(256) void tgemm_sk(
    const u16* __restrict__ A, const u16* __restrict__ Bt,
    float* __restrict__ P, int M, int N, int K, int KS)
{
    constexpr int BM = 128, BN = 64, BK = 64;
    __shared__ __align__(16) u16 As[BM * BK];
    __shared__ __align__(16) u16 Bs[BN * BK];

    const int bm0 = blockIdx.y * BM, bn0 = blockIdx.x * BN;
    const int kz = blockIdx.z;
    const int tid = threadIdx.x;
    const int lane = tid & 63;
    const int wave = tid >> 6;
    const int wr = wave >> 1;
    const int wc = wave & 1;
    const int lr = lane & 15;
    const int srow = lane >> 3;
    const int schk = lane & 7;

    f4v acc[4][2] = {};

    const int kend = kz * KS + KS;
    for (int k0 = kz * KS; k0 < kend; k0 += BK) {
#pragma unroll
        for (int ci = 0; ci < 4; ci++) {
            const int r8 = (wave * 4 + ci) * 8;
            const int row = r8 + srow;
            const int gchk = schk ^ (row & 7);
            GLL(A + (size_t)(bm0 + row) * K + k0 + gchk * 8, &As[r8 * 64]);
        }
#pragma unroll
        for (int ci = 0; ci < 2; ci++) {
            const int r8 = (wave * 2 + ci) * 8;
            const int row = r8 + srow;
            int gn = bn0 + row;
            if (gn >= N) gn = N - 1;
            const int gchk = schk ^ (row & 7);
            GLL(Bt + (size_t)gn * K + k0 + gchk * 8, &Bs[r8 * 64]);
        }
        __syncthreads();
#pragma unroll
        for (int kk = 0; kk < 2; kk++) {
            const int cbase = (lane >> 4) + kk * 4;
            s8v a[4], b[2];
#pragma unroll
            for (int m = 0; m < 4; m++) {
                const int row = wr * 64 + m * 16 + lr;
                a[m] = *(const s8v*)&As[row * 64 + (cbase ^ (row & 7)) * 8];
            }
#pragma unroll
            for (int n = 0; n < 2; n++) {
                const int row = wc * 32 + n * 16 + lr;
                b[n] = *(const s8v*)&Bs[row * 64 + (cbase ^ (row & 7)) * 8];
            }
#pragma unroll
            for (int m = 0; m < 4; m++)
#pragma unroll
                for (int n = 0; n < 2; n++)
                    acc[m][n] = mfma_bf16(a[m], b[n], acc[m][n]);
        }
        __syncthreads();
    }

    float* Pz = P + (size_t)kz * M * N;
#pragma unroll
    for (int m = 0; m < 4; m++)
#pragma unroll
        for (int n = 0; n < 2; n++)
#pragma unroll
            for (int i = 0; i < 4; i++) {
                int gm = bm0 + wr * 64 + m * 16 + (lane >> 4) * 4 + i;
                int gn = bn0 + wc * 32 + n * 16 + lr;
                if (gm < M && gn < N)
                    Pz[(size_t)gm * N + gn] = acc[m][n][i];
            }
}

__global__ __launch_bounds__(256) void skred_kernel(
    const float* __restrict__ P, u16* __restrict__ out, int total, int sk)
{
    int i = blockIdx.x * 256 + threadIdx.x;
    if (i >= total) return;
    float s = 0.f;
    for (int z = 0; z < sk; z++) s += P[(size_t)z * total + i];
    out[i] = f2bf(s > 0.f ? s : expm1f(s));
}

// ------------------------------------------------------------- tgemm2 ----
// Weight-GEMM fast path: C[M,N] = A[M,K] @ B[K,N], bf16 out, no epilogue.
// A: bf16 pre-split hi(+lo if ASP) [M,K] row-major (K padded to %64).
// B: pre-split+transposed Bt hi/lo [N,K]. 3-term: a0b0 + a0b1 (+ a1b0).
template<bool ASP>
__global__ __launch_bounds__(256) void tgemm2(
    const u16* __restrict__ A0, const u16* __restrict__ A1,
    const u16* __restrict__ Bt0, const u16* __restrict__ Bt1,
    u16* __restrict__ C, int M, int N, int K)
{
    constexpr int BM = 128, BN = 64, BK = 64;
    __shared__ __align__(16) u16 As0[BM * BK];
    __shared__ __align__(16) u16 As1[ASP ? BM * BK : 8];
    __shared__ __align__(16) u16 Bs0[BN * BK];
    __shared__ __align__(16) u16 Bs1[BN * BK];

    const int bm0 = blockIdx.y * BM, bn0 = blockIdx.x * BN;
    const int tid = threadIdx.x;
    const int lane = tid & 63;
    const int wave = tid >> 6;
    const int wr = wave >> 1;
    const int wc = wave & 1;
    const int lr = lane & 15;
    const int srow = lane >> 3;
    const int schk = lane & 7;

    f4v acc[4][2] = {};

    for (int k0 = 0; k0 < K; k0 += BK) {
#pragma unroll
        for (int ci = 0; ci < 4; ci++) {
            const int r8 = (wave * 4 + ci) * 8;
            const int row = r8 + srow;
            const int gchk = schk ^ (row & 7);
            const size_t goff = (size_t)(bm0 + row) * K + k0 + gchk * 8;
            GLL(A0 + goff, &As0[r8 * 64]);
            if constexpr (ASP) GLL(A1 + goff, &As1[r8 * 64]);
        }
#pragma unroll
        for (int ci = 0; ci < 2; ci++) {
            const int r8 = (wave * 2 + ci) * 8;
            const int row = r8 + srow;
            int gn = bn0 + row;
            if (gn >= N) gn = N - 1;
            const int gchk = schk ^ (row & 7);
            const size_t goff = (size_t)gn * K + k0 + gchk * 8;
            GLL(Bt0 + goff, &Bs0[r8 * 64]);
            GLL(Bt1 + goff, &Bs1[r8 * 64]);
        }
        __syncthreads();

#pragma unroll
        for (int kk = 0; kk < 2; kk++) {
            const int cbase = (lane >> 4) + kk * 4;
            s8v a0[4], a1[ASP ? 4 : 1], b0[2], b1[2];
#pragma unroll
            for (int m = 0; m < 4; m++) {
                const int row = wr * 64 + m * 16 + lr;
                const int o = row * 64 + (cbase ^ (row & 7)) * 8;
                a0[m] = *(const s8v*)&As0[o];
                if constexpr (ASP) a1[m] = *(const s8v*)&As1[o];
            }
#pragma unroll
            for (int n = 0; n < 2; n++) {
                const int row = wc * 32 + n * 16 + lr;
                const int o = row * 64 + (cbase ^ (row & 7)) * 8;
                b0[n] = *(const s8v*)&Bs0[o];
                b1[n] = *(const s8v*)&Bs1[o];
            }
#pragma unroll
            for (int m = 0; m < 4; m++)
#pragma unroll
                for (int n = 0; n < 2; n++) {
                    acc[m][n] = mfma_bf16(a0[m], b0[n], acc[m][n]);
                    acc[m][n] = mfma_bf16(a0[m], b1[n], acc[m][n]);
                    if constexpr (ASP) acc[m][n] = mfma_bf16(a1[m], b0[n], acc[m][n]);
                }
        }
        __syncthreads();
    }

#pragma unroll
    for (int m = 0; m < 4; m++)
#pragma unroll
        for (int n = 0; n < 2; n++)
#pragma unroll
            for (int i = 0; i < 4; i++) {
                int gm = bm0 + wr * 64 + m * 16 + (lane >> 4) * 4 + i;
                int gn = bn0 + wc * 32 + n * 16 + lr;
                if (gm < M && gn < N)
                    C[(size_t)gm * N + gn] = f2bf(acc[m][n][i]);
            }
}

// -------------------------------------------------------------- splits ----
// f32 [M][C] -> hi/lo bf16 [M][Cp], zero-padded cols C..Cp.
__global__ __launch_bounds__(256) void splitA_kernel(
    const float* __restrict__ src, u16* __restrict__ hi, u16* __restrict__ lo,
    int C, int Cp)
{
    int r = blockIdx.y;
    int c = blockIdx.x * 256 + threadIdx.x;
    if (c >= Cp) return;
    float v = (c < C) ? src[(size_t)r * C + c] : 0.f;
    u16 h = f2bf(v);
    hi[(size_t)r * Cp + c] = h;
    lo[(size_t)r * Cp + c] = f2bf(v - bf2f(h));
}

// f32 src[R][C] -> hi/lo bf16 [C][Rp] (transposed), zero-padded rows R..Rp.
__global__ __launch_bounds__(256) void splitBT_kernel(
    const float* __restrict__ src, u16* __restrict__ hi, u16* __restrict__ lo,
    int R, int C, int Rp)
{
    __shared__ float t[32][33];
    const int r0 = blockIdx.y * 32, c0 = blockIdx.x * 32;
    const int tr = threadIdx.x >> 5, tc = threadIdx.x & 31;
#pragma unroll
    for (int i = 0; i < 4; i++) {
        int r = r0 + tr + i * 8, c = c0 + tc;
        t[tr + i * 8][tc] = (r < R && c < C) ? src[(size_t)r * C + c] : 0.f;
    }
    __syncthreads();
#pragma unroll
    for (int i = 0; i < 4; i++) {
        int c = c0 + tr + i * 8, r = r0 + tc;
        if (c < C && r < Rp) {
            float v = t[tc][tr + i * 8];
            u16 h = f2bf(v);
            hi[(size_t)c * Rp + r] = h;
            lo[(size_t)c * Rp + r] = f2bf(v - bf2f(h));
        }
    }
}

// ---------------------------------------------------------- transpose ----
__global__ __launch_bounds__(256) void tr_kernel(
    const u16* __restrict__ src, u16* __restrict__ dst, int R, int C)
{
    __shared__ u16 t[32][33];
    const int r0 = blockIdx.y * 32, c0 = blockIdx.x * 32;
    const int tr = threadIdx.x >> 5, tc = threadIdx.x & 31;
#pragma unroll
    for (int i = 0; i < 4; i++) {
        int r = r0 + tr + i * 8, c = c0 + tc;
        t[tr + i * 8][tc] = (r < R && c < C) ? src[(size_t)r * C + c] : (u16)0;
    }
    __syncthreads();
#pragma unroll
    for (int i = 0; i < 4; i++) {
        int c = c0 + tr + i * 8, r = r0 + tc;
        if (c < C && r < R) dst[(size_t)c * R + r] = t[tc][tr + i * 8];
    }
}

// ------------------------------------------------------------- reduce ----
__device__ __forceinline__ float block_sum4(float v, float* red) {
#pragma unroll
    for (int off = 32; off; off >>= 1) v += __shfl_down(v, off);
    int w = threadIdx.x >> 6;
    if ((threadIdx.x & 63) == 0) red[w] = v;
    __syncthreads();
    float r = red[0] + red[1] + red[2] + red[3];
    __syncthreads();
    return r;
}
__device__ __forceinline__ float block_max4(float v, float* red) {
#pragma unroll
    for (int off = 32; off; off >>= 1) v = fmaxf(v, __shfl_down(v, off));
    int w = threadIdx.x >> 6;
    if ((threadIdx.x & 63) == 0) red[w] = v;
    __syncthreads();
    float r = fmaxf(fmaxf(red[0], red[1]), fmaxf(red[2], red[3]));
    __syncthreads();
    return r;
}

// ------------------------------------------------------------- scores ----
__global__ __launch_bounds__(256) void scores_kernel(
    const u16* __restrict__ Wh, int ld, int F, const float* __restrict__ a,
    float* __restrict__ s1, float* __restrict__ s2)
{
    __shared__ float red[4];
    int i = blockIdx.x, tid = threadIdx.x;
    float acc1 = 0.f, acc2 = 0.f;
    for (int f = tid; f < F; f += 256) {
        float w = bf2f(Wh[(size_t)i * ld + f]);
        acc1 += w * a[f];
        acc2 += w * a[F + f];
    }
    acc1 = block_sum4(acc1, red);
    acc2 = block_sum4(acc2, red);
    if (tid == 0) { s1[i] = acc1; s2[i] = acc2; }
}

// ---------------------------------------------------------------- att ----
__global__ __launch_bounds__(256) void att_kernel(
    const u32* __restrict__ mask, const float* __restrict__ s1,
    const float* __restrict__ s2, u16* __restrict__ att, int n)
{
    __shared__ float red[4];
    int i = blockIdx.x, tid = threadIdx.x;
    float s1i = s1[i];
    int j0 = tid * 16;
    u32 w = mask[(size_t)i * (n >> 5) + (j0 >> 5)];
    u32 bits = (j0 & 16) ? (w >> 16) : (w & 0xFFFFu);

    float e[16];
    float mx = -3.0e38f;
#pragma unroll
    for (int t = 0; t < 16; t++) {
        float x = s1i + s2[j0 + t];
        x = x > 0.f ? x : 0.2f * x;
        e[t] = x;
        if ((bits >> t) & 1u) mx = fmaxf(mx, x);
    }
    mx = block_max4(mx, red);

    float sum = 0.f;
#pragma unroll
    for (int t = 0; t < 16; t++) {
        float pv = ((bits >> t) & 1u) ? expf(e[t] - mx) : 0.f;
        e[t] = pv;
        sum += pv;
    }
    sum = block_sum4(sum, red);
    float rinv = sum > 0.f ? 1.f / sum : 0.f;
#pragma unroll
    for (int t = 0; t < 16; t++)
        att[(size_t)i * n + j0 + t] = f2bf(e[t] * rinv);
}

// --------------------------------------------------------------- fuse ----
__global__ __launch_bounds__(64) void fuse_kernel(
    const u16* __restrict__ E1, const u16* __restrict__ E2,
    const float* __restrict__ W, const float* __restrict__ U,
    float* __restrict__ fused, float* __restrict__ alpha)
{
    __shared__ float e1[64], e2[64];
    int i = blockIdx.x, d = threadIdx.x;
    e1[d] = bf2f(E1[i * 64 + d]);
    e2[d] = bf2f(E2[i * 64 + d]);
    __syncthreads();
    float v1 = 0.f, v2 = 0.f;
#pragma unroll 8
    for (int f = 0; f < 64; f++) {
        float w = W[f * 64 + d];
        v1 += e1[f] * w;
        v2 += e2[f] * w;
    }
    v1 = tanhf(v1); v2 = tanhf(v2);
    float u = U[d];
    float p1 = v1 * u, p2 = v2 * u;
#pragma unroll
    for (int off = 32; off; off >>= 1) {
        p1 += __shfl_down(p1, off);
        p2 += __shfl_down(p2, off);
    }
    p1 = __shfl(p1, 0); p2 = __shfl(p2, 0);
    float m = fmaxf(p1, p2);
    float w1 = expf(p1 - m), w2 = expf(p2 - m);
    float a1 = w1 / (w1 + w2), a2 = w2 / (w1 + w2);
    fused[i * 64 + d] = a1 * e1[d] + a2 * e2[d];
    if (alpha != nullptr && d < 2) alpha[i * 2 + d] = (d == 0 ? a1 : a2);
}

// ------------------------------------------------------------- bitpack ----
__global__ void bitpack_kernel(const int* __restrict__ adj,
                               u32* __restrict__ mask, int nwords)
{
    int w = blockIdx.x * 256 + threadIdx.x;
    if (w >= nwords) return;
    const int* src = adj + (size_t)w * 32;
    u32 m = 0;
#pragma unroll
    for (int b = 0; b < 32; b++) m |= (src[b] > 0 ? 1u : 0u) << b;
    mask[w] = m;
}

// ------------------------------------------------------------- driver ----
extern "C" void kernel_launch(void* const* d_in, const int* in_sizes, int n_in,
                              void* d_out, int out_size, void* d_ws, size_t ws_size,
                              hipStream_t stream)
{
    const int N = 4096, DIN = 3000, DINP = 3008, DH = 512, DO = 64;
    const float* x      = (const float*)d_in[0];
    const int*   adjF   = (const int*)d_in[1];
    const int*   adjS   = (const int*)d_in[2];
    const float* We1    = (const float*)d_in[3];
    const float* aE1    = (const float*)d_in[4];
    const float* We2    = (const float*)d_in[5];
    const float* aE2    = (const float*)d_in[6];
    const float* Wd1    = (const float*)d_in[7];
    const float* aD1    = (const float*)d_in[8];
    const float* Wd2    = (const float*)d_in[9];
    const float* aD2    = (const float*)d_in[10];
    const float* Womega = (const float*)d_in[11];
    const float* Uomega = (const float*)d_in[12];

    float* out       = (float*)d_out;
    float* out_emb   = out;                          // [4096,64]
    float* out_recon = out + (size_t)N * DO;         // [4096,3000]
    float* out_corr  = out_recon + (size_t)N * DIN;  // [4096,64]
    float* out_alpha = out_corr + (size_t)N * DO;    // [4096,2]

    char* ws = (char*)d_ws;
    size_t off = 0;
    auto alloc = [&](size_t bytes) {
        size_t o = off; off += (bytes + 255) & ~(size_t)255; return o;
    };
    const size_t o_att   = alloc((size_t)N * N * 2);        // 33.6 MB
    const size_t o_maskF = alloc((size_t)N * (N / 32) * 4);
    const size_t o_maskS = alloc((size_t)N * (N / 32) * 4);
    const size_t o_s1    = alloc((size_t)N * 4);
    const size_t o_s2    = alloc((size_t)N * 4);
    const size_t o_wh1   = alloc((size_t)N * DH * 2);       // wh1x / whc1
    const size_t o_h1a   = alloc((size_t)N * DH * 2);       // h1f / c1f
    const size_t o_h1b   = alloc((size_t)N * DH * 2);       // h1s / c1s
    const size_t o_whd1  = alloc((size_t)N * DH * 2);
    const size_t o_d1    = alloc((size_t)N * DH * 2);
    const size_t o_whd2  = alloc((size_t)N * DIN * 2);      // 24.6 MB
    size_t o_b64[8];
    for (int i = 0; i < 8; i++) o_b64[i] = alloc((size_t)N * DO * 2);
    // transposed-B buffers for att-GEMMs
    const size_t o_t512  = alloc((size_t)DH * N * 2);
    const size_t o_td1   = alloc((size_t)DH * N * 2);
    const size_t o_td2   = alloc((size_t)DIN * N * 2);      // 24.6 MB
    const size_t o_t64a  = alloc((size_t)DO * N * 2);
    const size_t o_t64b  = alloc((size_t)DO * N * 2);
    // pre-split operands (xh/xl reused for recon split)
    const size_t o_xh    = alloc((size_t)N * DINP * 2);     // 24.7 MB
    const size_t o_xl    = alloc((size_t)N * DINP * 2);
    const size_t o_we1th = alloc((size_t)DH * DINP * 2);
    const size_t o_we1tl = alloc((size_t)DH * DINP * 2);
    const size_t o_we2th = alloc((size_t)DO * DH * 2);
    const size_t o_we2tl = alloc((size_t)DO * DH * 2);
    const size_t o_wd1th = alloc((size_t)DH * DO * 2);
    const size_t o_wd1tl = alloc((size_t)DH * DO * 2);
    const size_t o_wd2th = alloc((size_t)DIN * DH * 2);
    const size_t o_wd2tl = alloc((size_t)DIN * DH * 2);
    const size_t o_eh    = alloc((size_t)N * DO * 2);
    const size_t o_el    = alloc((size_t)N * DO * 2);
    const size_t o_skp   = alloc((size_t)8 * N * DO * 4);   // 8.4 MB

    u16* att    = (u16*)(ws + o_att);
    u32* maskF  = (u32*)(ws + o_maskF);
    u32* maskS  = (u32*)(ws + o_maskS);
    float* s1   = (float*)(ws + o_s1);
    float* s2   = (float*)(ws + o_s2);
    u16* wh1x   = (u16*)(ws + o_wh1);
    u16* whc1   = (u16*)(ws + o_wh1);
    u16* h1f    = (u16*)(ws + o_h1a);
    u16* c1f    = (u16*)(ws + o_h1a);
    u16* h1s    = (u16*)(ws + o_h1b);
    u16* c1s    = (u16*)(ws + o_h1b);
    u16* whd1   = (u16*)(ws + o_whd1);
    u16* d1b    = (u16*)(ws + o_d1);
    u16* whd2   = (u16*)(ws + o_whd2);
    u16* wh2f   = (u16*)(ws + o_b64[0]);
    u16* wh2s   = (u16*)(ws + o_b64[1]);
    u16* h2f    = (u16*)(ws + o_b64[2]);
    u16* h2s    = (u16*)(ws + o_b64[3]);
    u16* whc2f  = (u16*)(ws + o_b64[4]);
    u16* whc2s  = (u16*)(ws + o_b64[5]);
    u16* c2f    = (u16*)(ws + o_b64[6]);
    u16* c2s    = (u16*)(ws + o_b64[7]);
    u16* t512   = (u16*)(ws + o_t512);
    u16* td1    = (u16*)(ws + o_td1);
    u16* td2    = (u16*)(ws + o_td2);
    u16* t64a   = (u16*)(ws + o_t64a);
    u16* t64b   = (u16*)(ws + o_t64b);
    u16* xh     = (u16*)(ws + o_xh);
    u16* xl     = (u16*)(ws + o_xl);
    u16* we1th  = (u16*)(ws + o_we1th);
    u16* we1tl  = (u16*)(ws + o_we1tl);
    u16* we2th  = (u16*)(ws + o_we2th);
    u16* we2tl  = (u16*)(ws + o_we2tl);
    u16* wd1th  = (u16*)(ws + o_wd1th);
    u16* wd1tl  = (u16*)(ws + o_wd1tl);
    u16* wd2th  = (u16*)(ws + o_wd2th);
    u16* wd2tl  = (u16*)(ws + o_wd2tl);
    u16* eh     = (u16*)(ws + o_eh);
    u16* el     = (u16*)(ws + o_el);
    float* skp  = (float*)(ws + o_skp);

    auto grid = [](int M, int Nn) { return dim3((Nn + 63) / 64, (M + 127) / 128); };
    // att(bf16) @ Wh(via Wh^T), ELU
    auto gatt = [&](const u16* Bt, u16* C, int Nn) {
        tgemm<true, false><<<grid(N, Nn), 256, 0, stream>>>(att, Bt, C, N, Nn, N);
    };
    auto gatt_f32 = [&](const u16* Bt, float* C, int Nn) {
        tgemm<true, true><<<grid(N, Nn), 256, 0, stream>>>(att, Bt, C, N, Nn, N);
    };
    // small-N att-GEMM via split-K (8 slices of K=512) + reduce/ELU
    auto gatt_sk = [&](const u16* Bt, u16* C) {
        tgemm_sk<<<dim3(1, 32, 8), 256, 0, stream>>>(att, Bt, skp, N, DO, N, 512);
        skred_kernel<<<(N * DO + 255) / 256, 256, 0, stream>>>(skp, C, N * DO, 8);
    };
    // weight GEMM on pre-split operands
    auto wgemm_s = [&](const u16* A0, const u16* A1, const u16* Bt0, const u16* Bt1,
                       u16* C, int Nn, int K) {
        tgemm2<true><<<grid(N, Nn), 256, 0, stream>>>(A0, A1, Bt0, Bt1, C, N, Nn, K);
    };
    auto wgemm_h = [&](const u16* A0, const u16* Bt0, const u16* Bt1,
                       u16* C, int Nn, int K) {
        tgemm2<false><<<grid(N, Nn), 256, 0, stream>>>(A0, nullptr, Bt0, Bt1, C, N, Nn, K);
    };
    auto splitA = [&](const float* src, u16* hi, u16* lo, int C, int Cp) {
        splitA_kernel<<<dim3((Cp + 255) / 256, N), 256, 0, stream>>>(src, hi, lo, C, Cp);
    };
    auto splitBT = [&](const float* src, u16* hi, u16* lo, int R, int C, int Rp) {
        splitBT_kernel<<<dim3((C + 31) / 32, (Rp + 31) / 32), 256, 0, stream>>>(src, hi, lo, R, C, Rp);
    };
    auto tr = [&](const u16* src, u16* dst, int R, int C) {
        tr_kernel<<<dim3((C + 31) / 32, (R + 31) / 32), 256, 0, stream>>>(src, dst, R, C);
    };
    auto scores = [&](const u16* Wh, int ld, int F, const float* a) {
        scores_kernel<<<N, 256, 0, stream>>>(Wh, ld, F, a, s1, s2);
    };
    auto attb = [&](const u32* mask) {
        att_kernel<<<N, 256, 0, stream>>>(mask, s1, s2, att, N);
    };

    // ---- prep: bitmasks + operand pre-splits ----
    bitpack_kernel<<<(N * (N / 32) + 255) / 256, 256, 0, stream>>>(adjF, maskF, N * (N / 32));
    bitpack_kernel<<<(N * (N / 32) + 255) / 256, 256, 0, stream>>>(adjS, maskS, N * (N / 32));
    splitA(x, xh, xl, DIN, DINP);
    splitBT(We1, we1th, we1tl, DIN, DH, DINP);   // [512][3008]
    splitBT(We2, we2th, we2tl, DH, DO, DH);      // [64][512]
    splitBT(Wd1, wd1th, wd1tl, DO, DH, DO);      // [512][64]
    splitBT(Wd2, wd2th, wd2tl, DH, DIN, DH);     // [3000][512]

    // ---- encoder layer 1 (Wh shared across both adjacencies) ----
    wgemm_s(xh, xl, we1th, we1tl, wh1x, DH, DINP);
    tr(wh1x, t512, N, DH);
    scores(wh1x, DH, DH, aE1);
    attb(maskF); gatt(t512, h1f, DH);
    attb(maskS); gatt(t512, h1s, DH);

    // ---- encoder layer 2 ----
    wgemm_h(h1f, we2th, we2tl, wh2f, DO, DH);
    tr(wh2f, t64a, N, DO);
    scores(wh2f, DO, DO, aE2);
    attb(maskF); gatt_sk(t64a, h2f);
    wgemm_h(h1s, we2th, we2tl, wh2s, DO, DH);
    tr(wh2s, t64b, N, DO);
    scores(wh2s, DO, DO, aE2);
    attb(maskS); gatt_sk(t64b, h2s);

    // ---- fuse -> emb_latent (f32 in d_out) + alpha ----
    fuse_kernel<<<N, 64, 0, stream>>>(h2f, h2s, Womega, Uomega, out_emb, out_alpha);

    // ---- decoder layer 1 (spatial adj) ----
    splitA(out_emb, eh, el, DO, DO);
    wgemm_s(eh, el, wd1th, wd1tl, whd1, DH, DO);
    tr(whd1, td1, N, DH);
    scores(whd1, DH, DH, aD1);
    attb(maskS); gatt(td1, d1b, DH);

    // ---- decoder layer 2 (spatial adj); recon (f32) into d_out ----
    wgemm_h(d1b, wd2th, wd2tl, whd2, DIN, DH);
    tr(whd2, td2, N, DIN);
    scores(whd2, DIN, DIN, aD2);
    attb(maskS); gatt_f32(td2, out_recon, DIN);

    // ---- corr encoder layer 1 (A = recon, re-split into xh/xl) ----
    splitA(out_recon, xh, xl, DIN, DINP);
    wgemm_s(xh, xl, we1th, we1tl, whc1, DH, DINP);
    tr(whc1, t512, N, DH);
    scores(whc1, DH, DH, aE1);
    attb(maskF); gatt(t512, c1f, DH);
    attb(maskS); gatt(t512, c1s, DH);

    // ---- corr encoder layer 2 ----
    wgemm_h(c1f, we2th, we2tl, whc2f, DO, DH);
    tr(whc2f, t64a, N, DO);
    scores(whc2f, DO, DO, aE2);
    attb(maskF); gatt_sk(t64a, c2f);
    wgemm_h(c1s, we2th, we2tl, whc2s, DO, DH);
    tr(whc2s, t64b, N, DO);
    scores(whc2s, DO, DO, aE2);
    attb(maskS); gatt_sk(t64b, c2s);

    // ---- fuse -> corr (f32 in d_out) ----
    fuse_kernel<<<N, 64, 0, stream>>>(c2f, c2s, Womega, Uomega, out_corr, nullptr);
}

// Round 6
// 1087.087 us; speedup vs baseline: 10.2966x; 1.2154x over previous
//
#include <hip/hip_runtime.h>
#include <hip/hip_bf16.h>
#include <math.h>

using u16 = unsigned short;
using u32 = unsigned int;

typedef __attribute__((ext_vector_type(8))) short s8v;    // 8 x bf16 bits (4 VGPRs)
typedef __attribute__((ext_vector_type(4))) float f4v;    // MFMA acc

__device__ __forceinline__ float bf2f(u16 u) {
    u32 x = ((u32)u) << 16;
    return __builtin_bit_cast(float, x);
}
__device__ __forceinline__ u16 f2bf(float f) {
    u32 x = __builtin_bit_cast(u32, f);
    x += 0x7fffu + ((x >> 16) & 1u);
    return (u16)(x >> 16);
}

__device__ __forceinline__ f4v mfma_bf16(s8v a, s8v b, f4v c) {
    return __builtin_amdgcn_mfma_f32_16x16x32_bf16(a, b, c, 0, 0, 0);
}

#define GLL(srcp, dstp) __builtin_amdgcn_global_load_lds( \
    (const __attribute__((address_space(1))) void*)(srcp), \
    (__attribute__((address_space(3))) void*)(dstp), 16, 0, 0)

// Bijective XCD swizzle (m204): contiguous j-chunks per XCD, x-fastest within.
__device__ __forceinline__ void xcd_swz(int& bx, int& by, int& bz) {
    const int nx = gridDim.x, ny = gridDim.y;
    const int total = nx * ny * gridDim.z;
    int i = (bz * ny + by) * nx + bx;
    const int q = total >> 3, r = total & 7;
    const int xcd = i & 7, k = i >> 3;
    int j = ((xcd < r) ? xcd * (q + 1) : r * (q + 1) + (xcd - r) * q) + k;
    bx = j % nx; j /= nx;
    by = j % ny;
    bz = j / ny;
}

// ------------------------------------------------------------- tgemm ----
// att-GEMM fast path: C[M,N] = A[M,K] @ B[K,N], A bf16 [M,K] row-major,
// Bt[N,K] bf16 (k-contiguous). global_load_lds width=16, linear LDS with XOR
// chunk swizzle. 2-phase double-buffer: STAGE(next) issued before compute of
// current; one __syncthreads per K-step (vmcnt(0) drain is post-compute).
// Requires M%128==0, K%64==0. N arbitrary. BM=128 BN=64 BK=64; 4 waves 2x2.
template<bool DO_ELU, bool OUT_F32>
__global__ __launch_bounds__(256) void tgemm(
    const u16* __restrict__ A, const u16* __restrict__ Bt,
    void* __restrict__ Cv, int M, int N, int K)
{
    constexpr int BM = 128, BN = 64, BK = 64;
    __shared__ __align__(16) u16 As[2][BM * BK];   // 2 x 16 KB
    __shared__ __align__(16) u16 Bs[2][BN * BK];   // 2 x 8 KB

    int bx = blockIdx.x, by = blockIdx.y, bz = blockIdx.z;
    xcd_swz(bx, by, bz);
    const int bm0 = by * BM, bn0 = bx * BN;
    const int tid = threadIdx.x;
    const int lane = tid & 63;
    const int wave = tid >> 6;
    const int wr = wave >> 1;
    const int wc = wave & 1;
    const int lr = lane & 15;
    const int srow = lane >> 3;
    const int schk = lane & 7;

    f4v acc[4][2] = {};

    auto stage = [&](int buf, int k0) {
#pragma unroll
        for (int ci = 0; ci < 4; ci++) {
            const int r8 = (wave * 4 + ci) * 8;
            const int row = r8 + srow;
            const int gchk = schk ^ (row & 7);
            GLL(A + (size_t)(bm0 + row) * K + k0 + gchk * 8, &As[buf][r8 * 64]);
        }
#pragma unroll
        for (int ci = 0; ci < 2; ci++) {
            const int r8 = (wave * 2 + ci) * 8;
            const int row = r8 + srow;
            int gn = bn0 + row;
            if (gn >= N) gn = N - 1;
            const int gchk = schk ^ (row & 7);
            GLL(Bt + (size_t)gn * K + k0 + gchk * 8, &Bs[buf][r8 * 64]);
        }
    };

    stage(0, 0);
    __syncthreads();
    int cur = 0;
    for (int k0 = 0; k0 < K; k0 += BK) {
        if (k0 + BK < K) stage(cur ^ 1, k0 + BK);
#pragma unroll
        for (int kk = 0; kk < 2; kk++) {
            const int cbase = (lane >> 4) + kk * 4;
            s8v a[4], b[2];
#pragma unroll
            for (int m = 0; m < 4; m++) {
                const int row = wr * 64 + m * 16 + lr;
                a[m] = *(const s8v*)&As[cur][row * 64 + (cbase ^ (row & 7)) * 8];
            }
#pragma unroll
            for (int n = 0; n < 2; n++) {
                const int row = wc * 32 + n * 16 + lr;
                b[n] = *(const s8v*)&Bs[cur][row * 64 + (cbase ^ (row & 7)) * 8];
            }
#pragma unroll
            for (int m = 0; m < 4; m++)
#pragma unroll
                for (int n = 0; n < 2; n++)
                    acc[m][n] = mfma_bf16(a[m], b[n], acc[m][n]);
        }
        __syncthreads();
        cur ^= 1;
    }

#pragma unroll
    for (int m = 0; m < 4; m++)
#pragma unroll
        for (int n = 0; n < 2; n++)
#pragma unroll
            for (int i = 0; i < 4; i++) {
                int gm = bm0 + wr * 64 + m * 16 + (lane >> 4) * 4 + i;
                int gn = bn0 + wc * 32 + n * 16 + lr;
                if (gm < M && gn < N) {
                    float val = acc[m][n][i];
                    if (DO_ELU) val = val > 0.f ? val : expm1f(val);
                    if (OUT_F32) ((float*)Cv)[(size_t)gm * N + gn] = val;
                    else         ((u16*)Cv)[(size_t)gm * N + gn] = f2bf(val);
                }
            }
}

// ---------------------------------------------------------- tgemm_sk ----
// Split-K att-GEMM (N=64): grid.z slices K; f32 partials; skred finishes.
__global__ __launch_bounds__(256) void tgemm_sk(
    const u16* __restrict__ A, const u16* __restrict__ Bt,
    float* __restrict__ P, int M, int N, int K, int KS)
{
    constexpr int BM = 128, BN = 64, BK = 64;
    __shared__ __align__(16) u16 As[2][BM * BK];
    __shared__ __align__(16) u16 Bs[2][BN * BK];

    int bx = blockIdx.x, by = blockIdx.y, kz = blockIdx.z;
    xcd_swz(bx, by, kz);
    const int bm0 = by * BM, bn0 = bx * BN;
    const int tid = threadIdx.x;
    const int lane = tid & 63;
    const int wave = tid >> 6;
    const int wr = wave >> 1;
    const int wc = wave & 1;
    const int lr = lane & 15;
    const int srow = lane >> 3;
    const int schk = lane & 7;

    f4v acc[4][2] = {};

    auto stage = [&](int buf, int k0) {
#pragma unroll
        for (int ci = 0; ci < 4; ci++) {
            const int r8 = (wave * 4 + ci) * 8;
            const int row = r8 + srow;
            const int gchk = schk ^ (row & 7);
            GLL(A + (size_t)(bm0 + row) * K + k0 + gchk * 8, &As[buf][r8 * 64]);
        }
#pragma unroll
        for (int ci = 0; ci < 2; ci++) {
            const int r8 = (wave * 2 + ci) * 8;
            const int row = r8 + srow;
            int gn = bn0 + row;
            if (gn >= N) gn = N - 1;
            const int gchk = schk ^ (row & 7);
            GLL(Bt + (size_t)gn * K + k0 + gchk * 8, &Bs[buf][r8 * 64]);
        }
    };

    const int kbeg = kz * KS, kend = kbeg + KS;
    stage(0, kbeg);
    __syncthreads();
    int cur = 0;
    for (int k0 = kbeg; k0 < kend; k0 += BK) {
        if (k0 + BK < kend) stage(cur ^ 1, k0 + BK);
#pragma unroll
        for (int kk = 0; kk < 2; kk++) {
            const int cbase = (lane >> 4) + kk * 4;
            s8v a[4], b[2];
#pragma unroll
            for (int m = 0; m < 4; m++) {
                const int row = wr * 64 + m * 16 + lr;
                a[m] = *(const s8v*)&As[cur][row * 64 + (cbase ^ (row & 7)) * 8];
            }
#pragma unroll
            for (int n = 0; n < 2; n++) {
                const int row = wc * 32 + n * 16 + lr;
                b[n] = *(const s8v*)&Bs[cur][row * 64 + (cbase ^ (row & 7)) * 8];
            }
#pragma unroll
            for (int m = 0; m < 4; m++)
#pragma unroll
                for (int n = 0; n < 2; n++)
                    acc[m][n] = mfma_bf16(a[m], b[n], acc[m][n]);
        }
        __syncthreads();
        cur ^= 1;
    }

    float* Pz = P + (size_t)kz * M * N;
#pragma unroll
    for (int m = 0; m < 4; m++)
#pragma unroll
        for (int n = 0; n < 2; n++)
#pragma unroll
            for (int i = 0; i < 4; i++) {
                int gm = bm0 + wr * 64 + m * 16 + (lane >> 4) * 4 + i;
                int gn = bn0 + wc * 32 + n * 16 + lr;
                if (gm < M && gn < N)
                    Pz[(size_t)gm * N + gn] = acc[m][n][i];
            }
}

template<bool ELU>
__global__ __launch_bounds__(256) void skred_kernel(
    const float* __restrict__ P, u16* __restrict__ out, int total, int sk)
{
    int i = blockIdx.x * 256 + threadIdx.x;
    if (i >= total) return;
    float s = 0.f;
    for (int z = 0; z < sk; z++) s += P[(size_t)z * total + i];
    if (ELU) s = s > 0.f ? s : expm1f(s);
    out[i] = f2bf(s);
}

// ------------------------------------------------------------- tgemm2 ----
// Weight-GEMM path (pre-split bf16 hi/lo operands), single-buffered.
// SK: grid.z slices K, f32 partials to Cv (skred<false> finishes).
template<bool ASP, bool SK>
__global__ __launch_bounds__(256) void tgemm2(
    const u16* __restrict__ A0, const u16* __restrict__ A1,
    const u16* __restrict__ Bt0, const u16* __restrict__ Bt1,
    void* __restrict__ Cv, int M, int N, int K, int KS)
{
    constexpr int BM = 128, BN = 64, BK = 64;
    __shared__ __align__(16) u16 As0[BM * BK];
    __shared__ __align__(16) u16 As1[ASP ? BM * BK : 8];
    __shared__ __align__(16) u16 Bs0[BN * BK];
    __shared__ __align__(16) u16 Bs1[BN * BK];

    int bx = blockIdx.x, by = blockIdx.y, kz = blockIdx.z;
    xcd_swz(bx, by, kz);
    const int bm0 = by * BM, bn0 = bx * BN;
    const int tid = threadIdx.x;
    const int lane = tid & 63;
    const int wave = tid >> 6;
    const int wr = wave >> 1;
    const int wc = wave & 1;
    const int lr = lane & 15;
    const int srow = lane >> 3;
    const int schk = lane & 7;

    f4v acc[4][2] = {};

    const int kbeg = SK ? kz * KS : 0;
    const int kend = SK ? kbeg + KS : K;
    for (int k0 = kbeg; k0 < kend; k0 += BK) {
#pragma unroll
        for (int ci = 0; ci < 4; ci++) {
            const int r8 = (wave * 4 + ci) * 8;
            const int row = r8 + srow;
            const int gchk = schk ^ (row & 7);
            const size_t goff = (size_t)(bm0 + row) * K + k0 + gchk * 8;
            GLL(A0 + goff, &As0[r8 * 64]);
            if constexpr (ASP) GLL(A1 + goff, &As1[r8 * 64]);
        }
#pragma unroll
        for (int ci = 0; ci < 2; ci++) {
            const int r8 = (wave * 2 + ci) * 8;
            const int row = r8 + srow;
            int gn = bn0 + row;
            if (gn >= N) gn = N - 1;
            const int gchk = schk ^ (row & 7);
            const size_t goff = (size_t)gn * K + k0 + gchk * 8;
            GLL(Bt0 + goff, &Bs0[r8 * 64]);
            GLL(Bt1 + goff, &Bs1[r8 * 64]);
        }
        __syncthreads();

#pragma unroll
        for (int kk = 0; kk < 2; kk++) {
            const int cbase = (lane >> 4) + kk * 4;
            s8v a0[4], a1[ASP ? 4 : 1], b0[2], b1[2];
#pragma unroll
            for (int m = 0; m < 4; m++) {
                const int row = wr * 64 + m * 16 + lr;
                const int o = row * 64 + (cbase ^ (row & 7)) * 8;
                a0[m] = *(const s8v*)&As0[o];
                if constexpr (ASP) a1[m] = *(const s8v*)&As1[o];
            }
#pragma unroll
            for (int n = 0; n < 2; n++) {
                const int row = wc * 32 + n * 16 + lr;
                const int o = row * 64 + (cbase ^ (row & 7)) * 8;
                b0[n] = *(const s8v*)&Bs0[o];
                b1[n] = *(const s8v*)&Bs1[o];
            }
#pragma unroll
            for (int m = 0; m < 4; m++)
#pragma unroll
                for (int n = 0; n < 2; n++) {
                    acc[m][n] = mfma_bf16(a0[m], b0[n], acc[m][n]);
                    acc[m][n] = mfma_bf16(a0[m], b1[n], acc[m][n]);
                    if constexpr (ASP) acc[m][n] = mfma_bf16(a1[m], b0[n], acc[m][n]);
                }
        }
        __syncthreads();
    }

#pragma unroll
    for (int m = 0; m < 4; m++)
#pragma unroll
        for (int n = 0; n < 2; n++)
#pragma unroll
            for (int i = 0; i < 4; i++) {
                int gm = bm0 + wr * 64 + m * 16 + (lane >> 4) * 4 + i;
                int gn = bn0 + wc * 32 + n * 16 + lr;
                if (gm < M && gn < N) {
                    if (SK) ((float*)Cv)[(size_t)kz * M * N + (size_t)gm * N + gn] = acc[m][n][i];
                    else    ((u16*)Cv)[(size_t)gm * N + gn] = f2bf(acc[m][n][i]);
                }
            }
}

// -------------------------------------------------------------- splits ----
__global__ __launch_bounds__(256) void splitA_kernel(
    const float* __restrict__ src, u16* __restrict__ hi, u16* __restrict__ lo,
    int C, int Cp)
{
    int r = blockIdx.y;
    int c = blockIdx.x * 256 + threadIdx.x;
    if (c >= Cp) return;
    float v = (c < C) ? src[(size_t)r * C + c] : 0.f;
    u16 h = f2bf(v);
    hi[(size_t)r * Cp + c] = h;
    lo[(size_t)r * Cp + c] = f2bf(v - bf2f(h));
}

__global__ __launch_bounds__(256) void splitBT_kernel(
    const float* __restrict__ src, u16* __restrict__ hi, u16* __restrict__ lo,
    int R, int C, int Rp)
{
    __shared__ float t[32][33];
    const int r0 = blockIdx.y * 32, c0 = blockIdx.x * 32;
    const int tr = threadIdx.x >> 5, tc = threadIdx.x & 31;
#pragma unroll
    for (int i = 0; i < 4; i++) {
        int r = r0 + tr + i * 8, c = c0 + tc;
        t[tr + i * 8][tc] = (r < R && c < C) ? src[(size_t)r * C + c] : 0.f;
    }
    __syncthreads();
#pragma unroll
    for (int i = 0; i < 4; i++) {
        int c = c0 + tr + i * 8, r = r0 + tc;
        if (c < C && r < Rp) {
            float v = t[tc][tr + i * 8];
            u16 h = f2bf(v);
            hi[(size_t)c * Rp + r] = h;
            lo[(size_t)c * Rp + r] = f2bf(v - bf2f(h));
        }
    }
}

// ---------------------------------------------------------- transpose ----
__global__ __launch_bounds__(256) void tr_kernel(
    const u16* __restrict__ src, u16* __restrict__ dst, int R, int C)
{
    __shared__ u16 t[32][33];
    const int r0 = blockIdx.y * 32, c0 = blockIdx.x * 32;
    const int tr = threadIdx.x >> 5, tc = threadIdx.x & 31;
#pragma unroll
    for (int i = 0; i < 4; i++) {
        int r = r0 + tr + i * 8, c = c0 + tc;
        t[tr + i * 8][tc] = (r < R && c < C) ? src[(size_t)r * C + c] : (u16)0;
    }
    __syncthreads();
#pragma unroll
    for (int i = 0; i < 4; i++) {
        int c = c0 + tr + i * 8, r = r0 + tc;
        if (c < C && r < R) dst[(size_t)c * R + r] = t[tc][tr + i * 8];
    }
}

// ------------------------------------------------------------- reduce ----
__device__ __forceinline__ float block_sum4(float v, float* red) {
#pragma unroll
    for (int off = 32; off; off >>= 1) v += __shfl_down(v, off);
    int w = threadIdx.x >> 6;
    if ((threadIdx.x & 63) == 0) red[w] = v;
    __syncthreads();
    float r = red[0] + red[1] + red[2] + red[3];
    __syncthreads();
    return r;
}
__device__ __forceinline__ float block_max4(float v, float* red) {
#pragma unroll
    for (int off = 32; off; off >>= 1) v = fmaxf(v, __shfl_down(v, off));
    int w = threadIdx.x >> 6;
    if ((threadIdx.x & 63) == 0) red[w] = v;
    __syncthreads();
    float r = fmaxf(fmaxf(red[0], red[1]), fmaxf(red[2], red[3]));
    __syncthreads();
    return r;
}

// ------------------------------------------------------------- scores ----
__global__ __launch_bounds__(256) void scores_kernel(
    const u16* __restrict__ Wh, int ld, int F, const float* __restrict__ a,
    float* __restrict__ s1, float* __restrict__ s2)
{
    __shared__ float red[4];
    int i = blockIdx.x, tid = threadIdx.x;
    float acc1 = 0.f, acc2 = 0.f;
    for (int f = tid; f < F; f += 256) {
        float w = bf2f(Wh[(size_t)i * ld + f]);
        acc1 += w * a[f];
        acc2 += w * a[F + f];
    }
    acc1 = block_sum4(acc1, red);
    acc2 = block_sum4(acc2, red);
    if (tid == 0) { s1[i] = acc1; s2[i] = acc2; }
}

// ---------------------------------------------------------------- att ----
__global__ __launch_bounds__(256) void att_kernel(
    const u32* __restrict__ mask, const float* __restrict__ s1,
    const float* __restrict__ s2, u16* __restrict__ att, int n)
{
    __shared__ float red[4];
    int i = blockIdx.x, tid = threadIdx.x;
    float s1i = s1[i];
    int j0 = tid * 16;
    u32 w = mask[(size_t)i * (n >> 5) + (j0 >> 5)];
    u32 bits = (j0 & 16) ? (w >> 16) : (w & 0xFFFFu);

    float e[16];
    float mx = -3.0e38f;
#pragma unroll
    for (int t = 0; t < 16; t++) {
        float x = s1i + s2[j0 + t];
        x = x > 0.f ? x : 0.2f * x;
        e[t] = x;
        if ((bits >> t) & 1u) mx = fmaxf(mx, x);
    }
    mx = block_max4(mx, red);

    float sum = 0.f;
#pragma unroll
    for (int t = 0; t < 16; t++) {
        float pv = ((bits >> t) & 1u) ? expf(e[t] - mx) : 0.f;
        e[t] = pv;
        sum += pv;
    }
    sum = block_sum4(sum, red);
    float rinv = sum > 0.f ? 1.f / sum : 0.f;
#pragma unroll
    for (int t = 0; t < 16; t++)
        att[(size_t)i * n + j0 + t] = f2bf(e[t] * rinv);
}

// --------------------------------------------------------------- fuse ----
__global__ __launch_bounds__(64) void fuse_kernel(
    const u16* __restrict__ E1, const u16* __restrict__ E2,
    const float* __restrict__ W, const float* __restrict__ U,
    float* __restrict__ fused, float* __restrict__ alpha)
{
    __shared__ float e1[64], e2[64];
    int i = blockIdx.x, d = threadIdx.x;
    e1[d] = bf2f(E1[i * 64 + d]);
    e2[d] = bf2f(E2[i * 64 + d]);
    __syncthreads();
    float v1 = 0.f, v2 = 0.f;
#pragma unroll 8
    for (int f = 0; f < 64; f++) {
        float w = W[f * 64 + d];
        v1 += e1[f] * w;
        v2 += e2[f] * w;
    }
    v1 = tanhf(v1); v2 = tanhf(v2);
    float u = U[d];
    float p1 = v1 * u, p2 = v2 * u;
#pragma unroll
    for (int off = 32; off; off >>= 1) {
        p1 += __shfl_down(p1, off);
        p2 += __shfl_down(p2, off);
    }
    p1 = __shfl(p1, 0); p2 = __shfl(p2, 0);
    float m = fmaxf(p1, p2);
    float w1 = expf(p1 - m), w2 = expf(p2 - m);
    float a1 = w1 / (w1 + w2), a2 = w2 / (w1 + w2);
    fused[i * 64 + d] = a1 * e1[d] + a2 * e2[d];
    if (alpha != nullptr && d < 2) alpha[i * 2 + d] = (d == 0 ? a1 : a2);
}

// ------------------------------------------------------------- bitpack ----
__global__ void bitpack_kernel(const int* __restrict__ adj,
                               u32* __restrict__ mask, int nwords)
{
    int w = blockIdx.x * 256 + threadIdx.x;
    if (w >= nwords) return;
    const int* src = adj + (size_t)w * 32;
    u32 m = 0;
#pragma unroll
    for (int b = 0; b < 32; b++) m |= (src[b] > 0 ? 1u : 0u) << b;
    mask[w] = m;
}

// ------------------------------------------------------------- driver ----
extern "C" void kernel_launch(void* const* d_in, const int* in_sizes, int n_in,
                              void* d_out, int out_size, void* d_ws, size_t ws_size,
                              hipStream_t stream)
{
    const int N = 4096, DIN = 3000, DINP = 3008, DH = 512, DO = 64;
    const float* x      = (const float*)d_in[0];
    const int*   adjF   = (const int*)d_in[1];
    const int*   adjS   = (const int*)d_in[2];
    const float* We1    = (const float*)d_in[3];
    const float* aE1    = (const float*)d_in[4];
    const float* We2    = (const float*)d_in[5];
    const float* aE2    = (const float*)d_in[6];
    const float* Wd1    = (const float*)d_in[7];
    const float* aD1    = (const float*)d_in[8];
    const float* Wd2    = (const float*)d_in[9];
    const float* aD2    = (const float*)d_in[10];
    const float* Womega = (const float*)d_in[11];
    const float* Uomega = (const float*)d_in[12];

    float* out       = (float*)d_out;
    float* out_emb   = out;                          // [4096,64]
    float* out_recon = out + (size_t)N * DO;         // [4096,3000]
    float* out_corr  = out_recon + (size_t)N * DIN;  // [4096,64]
    float* out_alpha = out_corr + (size_t)N * DO;    // [4096,2]

    char* ws = (char*)d_ws;
    size_t off = 0;
    auto alloc = [&](size_t bytes) {
        size_t o = off; off += (bytes + 255) & ~(size_t)255; return o;
    };
    const size_t o_att   = alloc((size_t)2 * N * N * 2);    // attF|attS, 67 MB
    const size_t o_maskF = alloc((size_t)N * (N / 32) * 4);
    const size_t o_maskS = alloc((size_t)N * (N / 32) * 4);
    const size_t o_s1    = alloc((size_t)N * 4);
    const size_t o_s2    = alloc((size_t)N * 4);
    const size_t o_wh1   = alloc((size_t)N * DH * 2);       // wh1x / whc1
    const size_t o_h1    = alloc((size_t)2 * N * DH * 2);   // h1f|h1s (c1f|c1s)
    const size_t o_whd1  = alloc((size_t)N * DH * 2);
    const size_t o_d1    = alloc((size_t)N * DH * 2);
    const size_t o_whd2  = alloc((size_t)N * DIN * 2);      // 24.6 MB
    size_t o_b64[8];
    for (int i = 0; i < 8; i++) o_b64[i] = alloc((size_t)N * DO * 2);
    const size_t o_t512  = alloc((size_t)DH * N * 2);
    const size_t o_td1   = alloc((size_t)DH * N * 2);
    const size_t o_td2   = alloc((size_t)DIN * N * 2);      // 24.6 MB
    const size_t o_t64a  = alloc((size_t)DO * N * 2);
    const size_t o_t64b  = alloc((size_t)DO * N * 2);
    const size_t o_xh    = alloc((size_t)N * DINP * 2);
    const size_t o_xl    = alloc((size_t)N * DINP * 2);
    const size_t o_we1th = alloc((size_t)DH * DINP * 2);
    const size_t o_we1tl = alloc((size_t)DH * DINP * 2);
    const size_t o_we2th = alloc((size_t)DO * DH * 2);
    const size_t o_we2tl = alloc((size_t)DO * DH * 2);
    const size_t o_wd1th = alloc((size_t)DH * DO * 2);
    const size_t o_wd1tl = alloc((size_t)DH * DO * 2);
    const size_t o_wd2th = alloc((size_t)DIN * DH * 2);
    const size_t o_wd2tl = alloc((size_t)DIN * DH * 2);
    const size_t o_eh    = alloc((size_t)N * DO * 2);
    const size_t o_el    = alloc((size_t)N * DO * 2);
    const size_t o_skp   = alloc((size_t)8 * N * DO * 4);   // 8.4 MB

    u16* attF   = (u16*)(ws + o_att);
    u16* attS   = attF + (size_t)N * N;                     // contiguous stack
    u32* maskF  = (u32*)(ws + o_maskF);
    u32* maskS  = (u32*)(ws + o_maskS);
    float* s1   = (float*)(ws + o_s1);
    float* s2   = (float*)(ws + o_s2);
    u16* wh1x   = (u16*)(ws + o_wh1);
    u16* whc1   = (u16*)(ws + o_wh1);
    u16* h1     = (u16*)(ws + o_h1);
    u16* h1f    = h1;
    u16* h1s    = h1 + (size_t)N * DH;
    u16* c1f    = h1f;
    u16* c1s    = h1s;
    u16* whd1   = (u16*)(ws + o_whd1);
    u16* d1b    = (u16*)(ws + o_d1);
    u16* whd2   = (u16*)(ws + o_whd2);
    u16* wh2f   = (u16*)(ws + o_b64[0]);
    u16* wh2s   = (u16*)(ws + o_b64[1]);
    u16* h2f    = (u16*)(ws + o_b64[2]);
    u16* h2s    = (u16*)(ws + o_b64[3]);
    u16* whc2f  = (u16*)(ws + o_b64[4]);
    u16* whc2s  = (u16*)(ws + o_b64[5]);
    u16* c2f    = (u16*)(ws + o_b64[6]);
    u16* c2s    = (u16*)(ws + o_b64[7]);
    u16* t512   = (u16*)(ws + o_t512);
    u16* td1    = (u16*)(ws + o_td1);
    u16* td2    = (u16*)(ws + o_td2);
    u16* t64a   = (u16*)(ws + o_t64a);
    u16* t64b   = (u16*)(ws + o_t64b);
    u16* xh     = (u16*)(ws + o_xh);
    u16* xl     = (u16*)(ws + o_xl);
    u16* we1th  = (u16*)(ws + o_we1th);
    u16* we1tl  = (u16*)(ws + o_we1tl);
    u16* we2th  = (u16*)(ws + o_we2th);
    u16* we2tl  = (u16*)(ws + o_we2tl);
    u16* wd1th  = (u16*)(ws + o_wd1th);
    u16* wd1tl  = (u16*)(ws + o_wd1tl);
    u16* wd2th  = (u16*)(ws + o_wd2th);
    u16* wd2tl  = (u16*)(ws + o_wd2tl);
    u16* eh     = (u16*)(ws + o_eh);
    u16* el     = (u16*)(ws + o_el);
    float* skp  = (float*)(ws + o_skp);

    auto grid = [](int M, int Nn) { return dim3((Nn + 63) / 64, (M + 127) / 128); };
    // att-GEMM (possibly stacked M): A bf16, Bt bf16, ELU
    auto gatt = [&](const u16* A, const u16* Bt, u16* C, int M, int Nn) {
        tgemm<true, false><<<grid(M, Nn), 256, 0, stream>>>(A, Bt, C, M, Nn, N);
    };
    auto gatt_f32 = [&](const u16* A, const u16* Bt, float* C, int Nn) {
        tgemm<true, true><<<grid(N, Nn), 256, 0, stream>>>(A, Bt, C, N, Nn, N);
    };
    // small-N att-GEMM via split-K (8 x K=512) + reduce/ELU
    auto gatt_sk = [&](const u16* A, const u16* Bt, u16* C) {
        tgemm_sk<<<dim3(1, 32, 8), 256, 0, stream>>>(A, Bt, skp, N, DO, N, 512);
        skred_kernel<true><<<(N * DO + 255) / 256, 256, 0, stream>>>(skp, C, N * DO, 8);
    };
    // weight GEMMs on pre-split operands
    auto wgemm_s = [&](const u16* A0, const u16* A1, const u16* Bt0, const u16* Bt1,
                       u16* C, int Nn, int K) {
        tgemm2<true, false><<<grid(N, Nn), 256, 0, stream>>>(A0, A1, Bt0, Bt1, C, N, Nn, K, K);
    };
    auto wgemm_h = [&](const u16* A0, const u16* Bt0, const u16* Bt1,
                       u16* C, int Nn, int K) {
        tgemm2<false, false><<<grid(N, Nn), 256, 0, stream>>>(A0, nullptr, Bt0, Bt1, C, N, Nn, K, K);
    };
    // N=64 weight GEMM via split-K (8 x K=64) + reduce (no ELU)
    auto wgemm64_sk = [&](const u16* A0, const u16* Bt0, const u16* Bt1, u16* C) {
        tgemm2<false, true><<<dim3(1, 32, 8), 256, 0, stream>>>(
            A0, nullptr, Bt0, Bt1, skp, N, DO, DH, 64);
        skred_kernel<false><<<(N * DO + 255) / 256, 256, 0, stream>>>(skp, C, N * DO, 8);
    };
    auto splitA = [&](const float* src, u16* hi, u16* lo, int C, int Cp) {
        splitA_kernel<<<dim3((Cp + 255) / 256, N), 256, 0, stream>>>(src, hi, lo, C, Cp);
    };
    auto splitBT = [&](const float* src, u16* hi, u16* lo, int R, int C, int Rp) {
        splitBT_kernel<<<dim3((C + 31) / 32, (Rp + 31) / 32), 256, 0, stream>>>(src, hi, lo, R, C, Rp);
    };
    auto tr = [&](const u16* src, u16* dst, int R, int C) {
        tr_kernel<<<dim3((C + 31) / 32, (R + 31) / 32), 256, 0, stream>>>(src, dst, R, C);
    };
    auto scores = [&](const u16* Wh, int ld, int F, const float* a) {
        scores_kernel<<<N, 256, 0, stream>>>(Wh, ld, F, a, s1, s2);
    };
    auto attb = [&](const u32* mask, u16* dst) {
        att_kernel<<<N, 256, 0, stream>>>(mask, s1, s2, dst, N);
    };

    // ---- prep: bitmasks + operand pre-splits ----
    bitpack_kernel<<<(N * (N / 32) + 255) / 256, 256, 0, stream>>>(adjF, maskF, N * (N / 32));
    bitpack_kernel<<<(N * (N / 32) + 255) / 256, 256, 0, stream>>>(adjS, maskS, N * (N / 32));
    splitA(x, xh, xl, DIN, DINP);
    splitBT(We1, we1th, we1tl, DIN, DH, DINP);   // [512][3008]
    splitBT(We2, we2th, we2tl, DH, DO, DH);      // [64][512]
    splitBT(Wd1, wd1th, wd1tl, DO, DH, DO);      // [512][64]
    splitBT(Wd2, wd2th, wd2tl, DH, DIN, DH);     // [3000][512]

    // ---- encoder layer 1 (stacked F|S att-GEMM, M=8192) ----
    wgemm_s(xh, xl, we1th, we1tl, wh1x, DH, DINP);
    tr(wh1x, t512, N, DH);
    scores(wh1x, DH, DH, aE1);
    attb(maskF, attF);
    attb(maskS, attS);
    gatt(attF, t512, h1, 2 * N, DH);             // h1f|h1s in one launch

    // ---- encoder layer 2 ----
    wgemm64_sk(h1f, we2th, we2tl, wh2f);
    tr(wh2f, t64a, N, DO);
    scores(wh2f, DO, DO, aE2);
    attb(maskF, attF); gatt_sk(attF, t64a, h2f);
    wgemm64_sk(h1s, we2th, we2tl, wh2s);
    tr(wh2s, t64b, N, DO);
    scores(wh2s, DO, DO, aE2);
    attb(maskS, attS); gatt_sk(attS, t64b, h2s);

    // ---- fuse -> emb_latent (f32 in d_out) + alpha ----
    fuse_kernel<<<N, 64, 0, stream>>>(h2f, h2s, Womega, Uomega, out_emb, out_alpha);

    // ---- decoder layer 1 (spatial adj) ----
    splitA(out_emb, eh, el, DO, DO);
    wgemm_s(eh, el, wd1th, wd1tl, whd1, DH, DO);
    tr(whd1, td1, N, DH);
    scores(whd1, DH, DH, aD1);
    attb(maskS, attS); gatt(attS, td1, d1b, N, DH);

    // ---- decoder layer 2 (spatial adj); recon (f32) into d_out ----
    wgemm_h(d1b, wd2th, wd2tl, whd2, DIN, DH);
    tr(whd2, td2, N, DIN);
    scores(whd2, DIN, DIN, aD2);
    attb(maskS, attS); gatt_f32(attS, td2, out_recon, DIN);

    // ---- corr encoder layer 1 (A = recon, re-split into xh/xl) ----
    splitA(out_recon, xh, xl, DIN, DINP);
    wgemm_s(xh, xl, we1th, we1tl, whc1, DH, DINP);
    tr(whc1, t512, N, DH);
    scores(whc1, DH, DH, aE1);
    attb(maskF, attF);
    attb(maskS, attS);
    gatt(attF, t512, h1, 2 * N, DH);             // c1f|c1s

    // ---- corr encoder layer 2 ----
    wgemm64_sk(c1f, we2th, we2tl, whc2f);
    tr(whc2f, t64a, N, DO);
    scores(whc2f, DO, DO, aE2);
    attb(maskF, attF); gatt_sk(attF, t64a, c2f);
    wgemm64_sk(c1s, we2th, we2tl, whc2s);
    tr(whc2s, t64b, N, DO);
    scores(whc2s, DO, DO, aE2);
    attb(maskS, attS); gatt_sk(attS, t64b, c2s);

    // ---- fuse -> corr (f32 in d_out) ----
    fuse_kernel<<<N, 64, 0, stream>>>(c2f, c2s, Womega, Uomega, out_corr, nullptr);
}

// Round 7
// 993.025 us; speedup vs baseline: 11.2719x; 1.0947x over previous
//
#include <hip/hip_runtime.h>
#include <hip/hip_bf16.h>
#include <math.h>

using u16 = unsigned short;
using u32 = unsigned int;

typedef __attribute__((ext_vector_type(8))) short s8v;    // 8 x bf16 bits (4 VGPRs)
typedef __attribute__((ext_vector_type(4))) float f4v;    // MFMA acc

__device__ __forceinline__ float bf2f(u16 u) {
    u32 x = ((u32)u) << 16;
    return __builtin_bit_cast(float, x);
}
__device__ __forceinline__ u16 f2bf(float f) {
    u32 x = __builtin_bit_cast(u32, f);
    x += 0x7fffu + ((x >> 16) & 1u);
    return (u16)(x >> 16);
}

__device__ __forceinline__ f4v mfma_bf16(s8v a, s8v b, f4v c) {
    return __builtin_amdgcn_mfma_f32_16x16x32_bf16(a, b, c, 0, 0, 0);
}

#define GLL(srcp, dstp) __builtin_amdgcn_global_load_lds( \
    (const __attribute__((address_space(1))) void*)(srcp), \
    (__attribute__((address_space(3))) void*)(dstp), 16, 0, 0)

// Bijective XCD swizzle (m204): contiguous j-chunks per XCD, x-fastest within.
__device__ __forceinline__ void xcd_swz(int& bx, int& by, int& bz) {
    const int nx = gridDim.x, ny = gridDim.y;
    const int total = nx * ny * gridDim.z;
    int i = (bz * ny + by) * nx + bx;
    const int q = total >> 3, r = total & 7;
    const int xcd = i & 7, k = i >> 3;
    int j = ((xcd < r) ? xcd * (q + 1) : r * (q + 1) + (xcd - r) * q) + k;
    bx = j % nx; j /= nx;
    by = j % ny;
    bz = j / ny;
}

// ------------------------------------------------------------- tgemm ----
// att-GEMM: C[M,N] = A[M,K] @ B[K,N], A bf16 [M,K], Bt[N,K] bf16.
// global_load_lds w=16, linear LDS + XOR chunk swizzle (chunk^=(row&7)),
// 2-phase double-buffer. M%128==0, K%64==0; N arbitrary.
// OUT_SPLIT (with OUT_F32): also writes bf16 hi/lo at stride Cp.
template<bool DO_ELU, bool OUT_F32, bool OUT_SPLIT>
__global__ __launch_bounds__(256) void tgemm(
    const u16* __restrict__ A, const u16* __restrict__ Bt,
    void* __restrict__ Cv, int M, int N, int K,
    u16* __restrict__ Sh, u16* __restrict__ Sl, int Cp)
{
    constexpr int BM = 128, BN = 64, BK = 64;
    __shared__ __align__(16) u16 As[2][BM * BK];
    __shared__ __align__(16) u16 Bs[2][BN * BK];

    int bx = blockIdx.x, by = blockIdx.y, bz = blockIdx.z;
    xcd_swz(bx, by, bz);
    const int bm0 = by * BM, bn0 = bx * BN;
    const int tid = threadIdx.x;
    const int lane = tid & 63;
    const int wave = tid >> 6;
    const int wr = wave >> 1, wc = wave & 1;
    const int lr = lane & 15;
    const int srow = lane >> 3, schk = lane & 7;

    f4v acc[4][2] = {};

    auto stage = [&](int buf, int k0) {
#pragma unroll
        for (int ci = 0; ci < 4; ci++) {
            const int r8 = (wave * 4 + ci) * 8;
            const int row = r8 + srow;
            const int gchk = schk ^ (row & 7);
            GLL(A + (size_t)(bm0 + row) * K + k0 + gchk * 8, &As[buf][r8 * 64]);
        }
#pragma unroll
        for (int ci = 0; ci < 2; ci++) {
            const int r8 = (wave * 2 + ci) * 8;
            const int row = r8 + srow;
            int gn = bn0 + row;
            if (gn >= N) gn = N - 1;
            const int gchk = schk ^ (row & 7);
            GLL(Bt + (size_t)gn * K + k0 + gchk * 8, &Bs[buf][r8 * 64]);
        }
    };

    stage(0, 0);
    __syncthreads();
    int cur = 0;
    for (int k0 = 0; k0 < K; k0 += BK) {
        if (k0 + BK < K) stage(cur ^ 1, k0 + BK);
#pragma unroll
        for (int kk = 0; kk < 2; kk++) {
            const int cbase = (lane >> 4) + kk * 4;
            s8v a[4], b[2];
#pragma unroll
            for (int m = 0; m < 4; m++) {
                const int row = wr * 64 + m * 16 + lr;
                a[m] = *(const s8v*)&As[cur][row * 64 + (cbase ^ (row & 7)) * 8];
            }
#pragma unroll
            for (int n = 0; n < 2; n++) {
                const int row = wc * 32 + n * 16 + lr;
                b[n] = *(const s8v*)&Bs[cur][row * 64 + (cbase ^ (row & 7)) * 8];
            }
#pragma unroll
            for (int m = 0; m < 4; m++)
#pragma unroll
                for (int n = 0; n < 2; n++)
                    acc[m][n] = mfma_bf16(a[m], b[n], acc[m][n]);
        }
        __syncthreads();
        cur ^= 1;
    }

#pragma unroll
    for (int m = 0; m < 4; m++)
#pragma unroll
        for (int n = 0; n < 2; n++)
#pragma unroll
            for (int i = 0; i < 4; i++) {
                int gm = bm0 + wr * 64 + m * 16 + (lane >> 4) * 4 + i;
                int gn = bn0 + wc * 32 + n * 16 + lr;
                if (gm < M && gn < N) {
                    float val = acc[m][n][i];
                    if (DO_ELU) val = val > 0.f ? val : expm1f(val);
                    if (OUT_F32) {
                        ((float*)Cv)[(size_t)gm * N + gn] = val;
                        if (OUT_SPLIT) {
                            u16 hv = f2bf(val);
                            Sh[(size_t)gm * Cp + gn] = hv;
                            Sl[(size_t)gm * Cp + gn] = f2bf(val - bf2f(hv));
                        }
                    } else {
                        ((u16*)Cv)[(size_t)gm * N + gn] = f2bf(val);
                    }
                }
            }
}

// ---------------------------------------------------------- tgemm_skd ----
// Dual-B stacked split-K att-GEMM (N=64): rows < Mh use BtA, else BtB.
// grid (1, M/128, z); f32 partials P[z][M][N].
__global__ __launch_bounds__(256) void tgemm_skd(
    const u16* __restrict__ A, const u16* __restrict__ BtA,
    const u16* __restrict__ BtB, float* __restrict__ P,
    int M, int Mh, int N, int K, int KS)
{
    constexpr int BM = 128, BN = 64, BK = 64;
    __shared__ __align__(16) u16 As[2][BM * BK];
    __shared__ __align__(16) u16 Bs[2][BN * BK];

    int bx = blockIdx.x, by = blockIdx.y, kz = blockIdx.z;
    xcd_swz(bx, by, kz);
    const int bm0 = by * BM, bn0 = bx * BN;
    const u16* Bt = (bm0 < Mh) ? BtA : BtB;
    const int tid = threadIdx.x;
    const int lane = tid & 63;
    const int wave = tid >> 6;
    const int wr = wave >> 1, wc = wave & 1;
    const int lr = lane & 15;
    const int srow = lane >> 3, schk = lane & 7;

    f4v acc[4][2] = {};

    auto stage = [&](int buf, int k0) {
#pragma unroll
        for (int ci = 0; ci < 4; ci++) {
            const int r8 = (wave * 4 + ci) * 8;
            const int row = r8 + srow;
            const int gchk = schk ^ (row & 7);
            GLL(A + (size_t)(bm0 + row) * K + k0 + gchk * 8, &As[buf][r8 * 64]);
        }
#pragma unroll
        for (int ci = 0; ci < 2; ci++) {
            const int r8 = (wave * 2 + ci) * 8;
            const int row = r8 + srow;
            int gn = bn0 + row;
            if (gn >= N) gn = N - 1;
            const int gchk = schk ^ (row & 7);
            GLL(Bt + (size_t)gn * K + k0 + gchk * 8, &Bs[buf][r8 * 64]);
        }
    };

    const int kbeg = kz * KS, kend = kbeg + KS;
    stage(0, kbeg);
    __syncthreads();
    int cur = 0;
    for (int k0 = kbeg; k0 < kend; k0 += BK) {
        if (k0 + BK < kend) stage(cur ^ 1, k0 + BK);
#pragma unroll
        for (int kk = 0; kk < 2; kk++) {
            const int cbase = (lane >> 4) + kk * 4;
            s8v a[4], b[2];
#pragma unroll
            for (int m = 0; m < 4; m++) {
                const int row = wr * 64 + m * 16 + lr;
                a[m] = *(const s8v*)&As[cur][row * 64 + (cbase ^ (row & 7)) * 8];
            }
#pragma unroll
            for (int n = 0; n < 2; n++) {
                const int row = wc * 32 + n * 16 + lr;
                b[n] = *(const s8v*)&Bs[cur][row * 64 + (cbase ^ (row & 7)) * 8];
            }
#pragma unroll
            for (int m = 0; m < 4; m++)
#pragma unroll
                for (int n = 0; n < 2; n++)
                    acc[m][n] = mfma_bf16(a[m], b[n], acc[m][n]);
        }
        __syncthreads();
        cur ^= 1;
    }

    float* Pz = P + (size_t)kz * M * N;
#pragma unroll
    for (int m = 0; m < 4; m++)
#pragma unroll
        for (int n = 0; n < 2; n++)
#pragma unroll
            for (int i = 0; i < 4; i++) {
                int gm = bm0 + wr * 64 + m * 16 + (lane >> 4) * 4 + i;
                int gn = bn0 + wc * 32 + n * 16 + lr;
                if (gm < M && gn < N)
                    Pz[(size_t)gm * N + gn] = acc[m][n][i];
            }
}

template<bool ELU>
__global__ __launch_bounds__(256) void skred_kernel(
    const float* __restrict__ P, u16* __restrict__ out, int total, int sk)
{
    int i = blockIdx.x * 256 + threadIdx.x;
    if (i >= total) return;
    float s = 0.f;
    for (int z = 0; z < sk; z++) s += P[(size_t)z * total + i];
    if (ELU) s = s > 0.f ? s : expm1f(s);
    out[i] = f2bf(s);
}

// ------------------------------------------------------------- tgemm2 ----
// Weight-GEMM (pre-split bf16 hi/lo), BK=32, 2-phase double-buffer.
// Chunk swizzle (row&3)^((row>>2)&1) keeps ds_read_b128 <=2-way.
// SK: grid.z slices K, f32 partials to Cv.
template<bool ASP, bool SK>
__global__ __launch_bounds__(256) void tgemm2(
    const u16* __restrict__ A0, const u16* __restrict__ A1,
    const u16* __restrict__ Bt0, const u16* __restrict__ Bt1,
    void* __restrict__ Cv, int M, int N, int K, int KS)
{
    constexpr int BM = 128, BN = 64, BK = 32;
    __shared__ __align__(16) u16 As0[2][BM * BK];
    __shared__ __align__(16) u16 As1[ASP ? 2 : 1][ASP ? BM * BK : 8];
    __shared__ __align__(16) u16 Bs0[2][BN * BK];
    __shared__ __align__(16) u16 Bs1[2][BN * BK];

    int bx = blockIdx.x, by = blockIdx.y, kz = blockIdx.z;
    xcd_swz(bx, by, kz);
    const int bm0 = by * BM, bn0 = bx * BN;
    const int tid = threadIdx.x;
    const int lane = tid & 63;
    const int wave = tid >> 6;
    const int wr = wave >> 1, wc = wave & 1;
    const int lr = lane & 15;
    const int srow = lane >> 2;      // 16 rows per 1KB wave-chunk
    const int schk = lane & 3;       // 4 chunks per 64B row

    auto swzr = [](int row) { return (row & 3) ^ ((row >> 2) & 1); };

    f4v acc[4][2] = {};

    auto stage = [&](int buf, int k0) {
#pragma unroll
        for (int ci = 0; ci < 2; ci++) {
            const int r16 = (wave * 2 + ci) * 16;
            const int row = r16 + srow;
            const int gchk = schk ^ swzr(row);
            const size_t goff = (size_t)(bm0 + row) * K + k0 + gchk * 8;
            GLL(A0 + goff, &As0[buf][r16 * 32]);
            if constexpr (ASP) GLL(A1 + goff, &As1[buf][r16 * 32]);
        }
        {
            const int r16 = wave * 16;
            const int row = r16 + srow;
            int gn = bn0 + row;
            if (gn >= N) gn = N - 1;
            const int gchk = schk ^ swzr(row);
            const size_t goff = (size_t)gn * K + k0 + gchk * 8;
            GLL(Bt0 + goff, &Bs0[buf][r16 * 32]);
            GLL(Bt1 + goff, &Bs1[buf][r16 * 32]);
        }
    };

    const int kbeg = SK ? kz * KS : 0;
    const int kend = SK ? kbeg + KS : K;
    stage(0, kbeg);
    __syncthreads();
    int cur = 0;
    for (int k0 = kbeg; k0 < kend; k0 += BK) {
        if (k0 + BK < kend) stage(cur ^ 1, k0 + BK);
        {
            const int cbase = lane >> 4;     // 0..3
            s8v a0[4], a1[ASP ? 4 : 1], b0[2], b1[2];
#pragma unroll
            for (int m = 0; m < 4; m++) {
                const int row = wr * 64 + m * 16 + lr;
                const int o = row * 32 + (cbase ^ swzr(row)) * 8;
                a0[m] = *(const s8v*)&As0[cur][o];
                if constexpr (ASP) a1[m] = *(const s8v*)&As1[cur][o];
            }
#pragma unroll
            for (int n = 0; n < 2; n++) {
                const int row = wc * 32 + n * 16 + lr;
                const int o = row * 32 + (cbase ^ swzr(row)) * 8;
                b0[n] = *(const s8v*)&Bs0[cur][o];
                b1[n] = *(const s8v*)&Bs1[cur][o];
            }
#pragma unroll
            for (int m = 0; m < 4; m++)
#pragma unroll
                for (int n = 0; n < 2; n++) {
                    acc[m][n] = mfma_bf16(a0[m], b0[n], acc[m][n]);
                    acc[m][n] = mfma_bf16(a0[m], b1[n], acc[m][n]);
                    if constexpr (ASP) acc[m][n] = mfma_bf16(a1[m], b0[n], acc[m][n]);
                }
        }
        __syncthreads();
        cur ^= 1;
    }

#pragma unroll
    for (int m = 0; m < 4; m++)
#pragma unroll
        for (int n = 0; n < 2; n++)
#pragma unroll
            for (int i = 0; i < 4; i++) {
                int gm = bm0 + wr * 64 + m * 16 + (lane >> 4) * 4 + i;
                int gn = bn0 + wc * 32 + n * 16 + lr;
                if (gm < M && gn < N) {
                    if (SK) ((float*)Cv)[(size_t)kz * M * N + (size_t)gm * N + gn] = acc[m][n][i];
                    else    ((u16*)Cv)[(size_t)gm * N + gn] = f2bf(acc[m][n][i]);
                }
            }
}

// ------------------------------------------------------------- skredTS ----
// Fused: split-K partial sum -> bf16 [2N][64] + transposed [64][N] halves
// + scores dot (s1,s2 stacked). 64 rows/block; thread = (row, 16-col group).
__global__ __launch_bounds__(256) void skredTS_kernel(
    const float* __restrict__ P, const float* __restrict__ a,
    u16* __restrict__ wh, u16* __restrict__ tA, u16* __restrict__ tB,
    float* __restrict__ s1, float* __restrict__ s2, int n, int sk)
{
    __shared__ u16 lds[64][72];
    const int rowbase = blockIdx.x * 64;
    const int t = threadIdx.x;
    const int rl = t >> 2, cg = t & 3;
    const int row = rowbase + rl;
    const size_t M2 = (size_t)2 * n;

    float v[16];
#pragma unroll
    for (int k = 0; k < 16; k++) v[k] = 0.f;
    for (int z = 0; z < sk; z++) {
        const float4* p = (const float4*)&P[((size_t)z * M2 + row) * 64 + cg * 16];
#pragma unroll
        for (int q = 0; q < 4; q++) {
            float4 x = p[q];
            v[q * 4 + 0] += x.x; v[q * 4 + 1] += x.y;
            v[q * 4 + 2] += x.z; v[q * 4 + 3] += x.w;
        }
    }
    u16 w[16];
    float p1 = 0.f, p2 = 0.f;
#pragma unroll
    for (int k = 0; k < 16; k++) {
        w[k] = f2bf(v[k]);
        float vr = bf2f(w[k]);
        int f = cg * 16 + k;
        p1 += vr * a[f];
        p2 += vr * a[64 + f];
    }
    *(s8v*)&wh[(size_t)row * 64 + cg * 16]     = *(s8v*)&w[0];
    *(s8v*)&wh[(size_t)row * 64 + cg * 16 + 8] = *(s8v*)&w[8];
    *(s8v*)&lds[rl][cg * 16]     = *(s8v*)&w[0];
    *(s8v*)&lds[rl][cg * 16 + 8] = *(s8v*)&w[8];

    p1 += __shfl_down(p1, 1); p1 += __shfl_down(p1, 2);
    p2 += __shfl_down(p2, 1); p2 += __shfl_down(p2, 2);
    if (cg == 0) { s1[row] = p1; s2[row] = p2; }
    __syncthreads();

    // transpose out: thread -> col rl, rows cg*16..+16
    const bool hb = rowbase >= n;
    u16* tX = hb ? tB : tA;
    const int grow = rowbase - (hb ? n : 0);
    u16 o[16];
#pragma unroll
    for (int k = 0; k < 16; k++) o[k] = lds[cg * 16 + k][rl];
    *(s8v*)&tX[(size_t)rl * n + grow + cg * 16]     = *(s8v*)&o[0];
    *(s8v*)&tX[(size_t)rl * n + grow + cg * 16 + 8] = *(s8v*)&o[8];
}

// -------------------------------------------------------------- splits ----
__global__ __launch_bounds__(256) void splitA_kernel(
    const float* __restrict__ src, u16* __restrict__ hi, u16* __restrict__ lo,
    int C, int Cp)
{
    int r = blockIdx.y;
    int c = blockIdx.x * 256 + threadIdx.x;
    if (c >= Cp) return;
    float v = (c < C) ? src[(size_t)r * C + c] : 0.f;
    u16 h = f2bf(v);
    hi[(size_t)r * Cp + c] = h;
    lo[(size_t)r * Cp + c] = f2bf(v - bf2f(h));
}

__global__ __launch_bounds__(256) void splitBT_kernel(
    const float* __restrict__ src, u16* __restrict__ hi, u16* __restrict__ lo,
    int R, int C, int Rp)
{
    __shared__ float t[32][33];
    const int r0 = blockIdx.y * 32, c0 = blockIdx.x * 32;
    const int tr = threadIdx.x >> 5, tc = threadIdx.x & 31;
#pragma unroll
    for (int i = 0; i < 4; i++) {
        int r = r0 + tr + i * 8, c = c0 + tc;
        t[tr + i * 8][tc] = (r < R && c < C) ? src[(size_t)r * C + c] : 0.f;
    }
    __syncthreads();
#pragma unroll
    for (int i = 0; i < 4; i++) {
        int c = c0 + tr + i * 8, r = r0 + tc;
        if (c < C && r < Rp) {
            float v = t[tc][tr + i * 8];
            u16 h = f2bf(v);
            hi[(size_t)c * Rp + r] = h;
            lo[(size_t)c * Rp + r] = f2bf(v - bf2f(h));
        }
    }
}

// ---------------------------------------------------------- transpose ----
__global__ __launch_bounds__(256) void tr_kernel(
    const u16* __restrict__ src, u16* __restrict__ dst, int R, int C)
{
    __shared__ u16 t[32][33];
    const int r0 = blockIdx.y * 32, c0 = blockIdx.x * 32;
    const int tr = threadIdx.x >> 5, tc = threadIdx.x & 31;
#pragma unroll
    for (int i = 0; i < 4; i++) {
        int r = r0 + tr + i * 8, c = c0 + tc;
        t[tr + i * 8][tc] = (r < R && c < C) ? src[(size_t)r * C + c] : (u16)0;
    }
    __syncthreads();
#pragma unroll
    for (int i = 0; i < 4; i++) {
        int c = c0 + tr + i * 8, r = r0 + tc;
        if (c < C && r < R) dst[(size_t)c * R + r] = t[tc][tr + i * 8];
    }
}

// ------------------------------------------------------------- reduce ----
__device__ __forceinline__ float block_sum4(float v, float* red) {
#pragma unroll
    for (int off = 32; off; off >>= 1) v += __shfl_down(v, off);
    int w = threadIdx.x >> 6;
    if ((threadIdx.x & 63) == 0) red[w] = v;
    __syncthreads();
    float r = red[0] + red[1] + red[2] + red[3];
    __syncthreads();
    return r;
}
__device__ __forceinline__ float block_max4(float v, float* red) {
#pragma unroll
    for (int off = 32; off; off >>= 1) v = fmaxf(v, __shfl_down(v, off));
    int w = threadIdx.x >> 6;
    if ((threadIdx.x & 63) == 0) red[w] = v;
    __syncthreads();
    float r = fmaxf(fmaxf(red[0], red[1]), fmaxf(red[2], red[3]));
    __syncthreads();
    return r;
}

// ------------------------------------------------------------- scores ----
__global__ __launch_bounds__(256) void scores_kernel(
    const u16* __restrict__ Wh, int ld, int F, const float* __restrict__ a,
    float* __restrict__ s1, float* __restrict__ s2)
{
    __shared__ float red[4];
    int i = blockIdx.x, tid = threadIdx.x;
    float acc1 = 0.f, acc2 = 0.f;
    for (int f = tid; f < F; f += 256) {
        float w = bf2f(Wh[(size_t)i * ld + f]);
        acc1 += w * a[f];
        acc2 += w * a[F + f];
    }
    acc1 = block_sum4(acc1, red);
    acc2 = block_sum4(acc2, red);
    if (tid == 0) { s1[i] = acc1; s2[i] = acc2; }
}

// ---------------------------------------------------------------- att ----
__device__ __forceinline__ void att_row(
    const u32* mask, const float* s1, const float* s2, int soff,
    u16* att, int i, int n, float* red)
{
    int tid = threadIdx.x;
    float s1i = s1[soff + i];
    int j0 = tid * 16;
    u32 w = mask[(size_t)i * (n >> 5) + (j0 >> 5)];
    u32 bits = (j0 & 16) ? (w >> 16) : (w & 0xFFFFu);

    float e[16];
    float mx = -3.0e38f;
#pragma unroll
    for (int t = 0; t < 16; t++) {
        float x = s1i + s2[soff + j0 + t];
        x = x > 0.f ? x : 0.2f * x;
        e[t] = x;
        if ((bits >> t) & 1u) mx = fmaxf(mx, x);
    }
    mx = block_max4(mx, red);

    float sum = 0.f;
#pragma unroll
    for (int t = 0; t < 16; t++) {
        float pv = ((bits >> t) & 1u) ? expf(e[t] - mx) : 0.f;
        e[t] = pv;
        sum += pv;
    }
    sum = block_sum4(sum, red);
    float rinv = sum > 0.f ? 1.f / sum : 0.f;
#pragma unroll
    for (int t = 0; t < 16; t++)
        att[(size_t)i * n + j0 + t] = f2bf(e[t] * rinv);
}

__global__ __launch_bounds__(256) void att_kernel(
    const u32* __restrict__ mask, const float* __restrict__ s1,
    const float* __restrict__ s2, u16* __restrict__ att, int n)
{
    __shared__ float red[4];
    att_row(mask, s1, s2, 0, att, blockIdx.x, n, red);
}

// dual: blocks [0,n) -> maskA/attA (soff 0); [n,2n) -> maskB/attB (soff offB)
__global__ __launch_bounds__(256) void att2_kernel(
    const u32* __restrict__ maskA, const u32* __restrict__ maskB,
    const float* __restrict__ s1, const float* __restrict__ s2, int offB,
    u16* __restrict__ attA, u16* __restrict__ attB, int n)
{
    __shared__ float red[4];
    int b = blockIdx.x;
    if (b < n) att_row(maskA, s1, s2, 0, attA, b, n, red);
    else      att_row(maskB, s1, s2, offB, attB, b - n, n, red);
}

// --------------------------------------------------------------- fuse ----
__global__ __launch_bounds__(64) void fuse_kernel(
    const u16* __restrict__ E1, const u16* __restrict__ E2,
    const float* __restrict__ W, const float* __restrict__ U,
    float* __restrict__ fused, float* __restrict__ alpha,
    u16* __restrict__ eh, u16* __restrict__ el)
{
    __shared__ float e1[64], e2[64];
    int i = blockIdx.x, d = threadIdx.x;
    e1[d] = bf2f(E1[i * 64 + d]);
    e2[d] = bf2f(E2[i * 64 + d]);
    __syncthreads();
    float v1 = 0.f, v2 = 0.f;
#pragma unroll 8
    for (int f = 0; f < 64; f++) {
        float w = W[f * 64 + d];
        v1 += e1[f] * w;
        v2 += e2[f] * w;
    }
    v1 = tanhf(v1); v2 = tanhf(v2);
    float u = U[d];
    float p1 = v1 * u, p2 = v2 * u;
#pragma unroll
    for (int off = 32; off; off >>= 1) {
        p1 += __shfl_down(p1, off);
        p2 += __shfl_down(p2, off);
    }
    p1 = __shfl(p1, 0); p2 = __shfl(p2, 0);
    float m = fmaxf(p1, p2);
    float w1 = expf(p1 - m), w2 = expf(p2 - m);
    float a1 = w1 / (w1 + w2), a2 = w2 / (w1 + w2);
    float fv = a1 * e1[d] + a2 * e2[d];
    fused[i * 64 + d] = fv;
    if (eh != nullptr) {
        u16 hv = f2bf(fv);
        eh[i * 64 + d] = hv;
        el[i * 64 + d] = f2bf(fv - bf2f(hv));
    }
    if (alpha != nullptr && d < 2) alpha[i * 2 + d] = (d == 0 ? a1 : a2);
}

// ------------------------------------------------------------- bitpack ----
__global__ void bitpack_kernel(const int* __restrict__ adj,
                               u32* __restrict__ mask, int nwords)
{
    int w = blockIdx.x * 256 + threadIdx.x;
    if (w >= nwords) return;
    const int* src = adj + (size_t)w * 32;
    u32 m = 0;
#pragma unroll
    for (int b = 0; b < 32; b++) m |= (src[b] > 0 ? 1u : 0u) << b;
    mask[w] = m;
}

// ------------------------------------------------------------- driver ----
extern "C" void kernel_launch(void* const* d_in, const int* in_sizes, int n_in,
                              void* d_out, int out_size, void* d_ws, size_t ws_size,
                              hipStream_t stream)
{
    const int N = 4096, DIN = 3000, DINP = 3008, DH = 512, DO = 64;
    const float* x      = (const float*)d_in[0];
    const int*   adjF   = (const int*)d_in[1];
    const int*   adjS   = (const int*)d_in[2];
    const float* We1    = (const float*)d_in[3];
    const float* aE1    = (const float*)d_in[4];
    const float* We2    = (const float*)d_in[5];
    const float* aE2    = (const float*)d_in[6];
    const float* Wd1    = (const float*)d_in[7];
    const float* aD1    = (const float*)d_in[8];
    const float* Wd2    = (const float*)d_in[9];
    const float* aD2    = (const float*)d_in[10];
    const float* Womega = (const float*)d_in[11];
    const float* Uomega = (const float*)d_in[12];

    float* out       = (float*)d_out;
    float* out_emb   = out;                          // [4096,64]
    float* out_recon = out + (size_t)N * DO;         // [4096,3000]
    float* out_corr  = out_recon + (size_t)N * DIN;  // [4096,64]
    float* out_alpha = out_corr + (size_t)N * DO;    // [4096,2]

    char* ws = (char*)d_ws;
    size_t off = 0;
    auto alloc = [&](size_t bytes) {
        size_t o = off; off += (bytes + 255) & ~(size_t)255; return o;
    };
    const size_t o_att   = alloc((size_t)2 * N * N * 2);    // attF|attS, 67 MB
    const size_t o_maskF = alloc((size_t)N * (N / 32) * 4);
    const size_t o_maskS = alloc((size_t)N * (N / 32) * 4);
    const size_t o_s1    = alloc((size_t)2 * N * 4);        // stacked scores
    const size_t o_s2    = alloc((size_t)2 * N * 4);
    const size_t o_wh1   = alloc((size_t)N * DH * 2);       // wh1x / whc1
    const size_t o_h1    = alloc((size_t)2 * N * DH * 2);   // h1f|h1s (c1)
    const size_t o_whd1  = alloc((size_t)N * DH * 2);
    const size_t o_d1    = alloc((size_t)N * DH * 2);
    const size_t o_whd2  = alloc((size_t)N * DIN * 2);      // 24.6 MB
    const size_t o_wh2   = alloc((size_t)2 * N * DO * 2);   // stacked wh2/whc2
    const size_t o_h2    = alloc((size_t)2 * N * DO * 2);   // stacked h2/c2
    const size_t o_t512  = alloc((size_t)DH * N * 2);
    const size_t o_td1   = alloc((size_t)DH * N * 2);
    const size_t o_td2   = alloc((size_t)DIN * N * 2);      // 24.6 MB
    const size_t o_t64a  = alloc((size_t)DO * N * 2);
    const size_t o_t64b  = alloc((size_t)DO * N * 2);
    const size_t o_xh    = alloc((size_t)N * DINP * 2);     // 24.7 MB
    const size_t o_xl    = alloc((size_t)N * DINP * 2);
    const size_t o_we1th = alloc((size_t)DH * DINP * 2);
    const size_t o_we1tl = alloc((size_t)DH * DINP * 2);
    const size_t o_we2th = alloc((size_t)DO * DH * 2);
    const size_t o_we2tl = alloc((size_t)DO * DH * 2);
    const size_t o_wd1th = alloc((size_t)DH * DO * 2);
    const size_t o_wd1tl = alloc((size_t)DH * DO * 2);
    const size_t o_wd2th = alloc((size_t)DIN * DH * 2);
    const size_t o_wd2tl = alloc((size_t)DIN * DH * 2);
    const size_t o_eh    = alloc((size_t)N * DO * 2);
    const size_t o_el    = alloc((size_t)N * DO * 2);
    const size_t o_skp   = alloc((size_t)8 * 2 * N * DO * 4); // 16.8 MB

    u16* attF   = (u16*)(ws + o_att);
    u16* attS   = attF + (size_t)N * N;
    u32* maskF  = (u32*)(ws + o_maskF);
    u32* maskS  = (u32*)(ws + o_maskS);
    float* s1   = (float*)(ws + o_s1);
    float* s2   = (float*)(ws + o_s2);
    u16* wh1x   = (u16*)(ws + o_wh1);
    u16* whc1   = (u16*)(ws + o_wh1);
    u16* h1     = (u16*)(ws + o_h1);
    u16* whd1   = (u16*)(ws + o_whd1);
    u16* d1b    = (u16*)(ws + o_d1);
    u16* whd2   = (u16*)(ws + o_whd2);
    u16* wh2    = (u16*)(ws + o_wh2);
    u16* h2     = (u16*)(ws + o_h2);
    u16* h2f    = h2;
    u16* h2s    = h2 + (size_t)N * DO;
    u16* t512   = (u16*)(ws + o_t512);
    u16* td1    = (u16*)(ws + o_td1);
    u16* td2    = (u16*)(ws + o_td2);
    u16* t64a   = (u16*)(ws + o_t64a);
    u16* t64b   = (u16*)(ws + o_t64b);
    u16* xh     = (u16*)(ws + o_xh);
    u16* xl     = (u16*)(ws + o_xl);
    u16* we1th  = (u16*)(ws + o_we1th);
    u16* we1tl  = (u16*)(ws + o_we1tl);
    u16* we2th  = (u16*)(ws + o_we2th);
    u16* we2tl  = (u16*)(ws + o_we2tl);
    u16* wd1th  = (u16*)(ws + o_wd1th);
    u16* wd1tl  = (u16*)(ws + o_wd1tl);
    u16* wd2th  = (u16*)(ws + o_wd2th);
    u16* wd2tl  = (u16*)(ws + o_wd2tl);
    u16* eh     = (u16*)(ws + o_eh);
    u16* el     = (u16*)(ws + o_el);
    float* skp  = (float*)(ws + o_skp);

    auto grid = [](int M, int Nn) { return dim3((Nn + 63) / 64, (M + 127) / 128); };
    auto gatt = [&](const u16* A, const u16* Bt, u16* C, int M, int Nn) {
        tgemm<true, false, false><<<grid(M, Nn), 256, 0, stream>>>(
            A, Bt, C, M, Nn, N, nullptr, nullptr, 0);
    };
    auto tr = [&](const u16* src, u16* dst, int R, int C) {
        tr_kernel<<<dim3((C + 31) / 32, (R + 31) / 32), 256, 0, stream>>>(src, dst, R, C);
    };
    auto scores = [&](const u16* Wh, int ld, int F, const float* a) {
        scores_kernel<<<N, 256, 0, stream>>>(Wh, ld, F, a, s1, s2);
    };
    // stacked layer-2 macro: wh2 = A(M=2N) @ We2 (split-K) -> skredTS ->
    // att2 -> dual-B split-K att-GEMM -> skred(ELU) -> h2out (stacked)
    auto layer2 = [&](const u16* Astacked, u16* wh2buf, u16* h2out) {
        tgemm2<false, true><<<dim3(1, 64, 8), 256, 0, stream>>>(
            Astacked, nullptr, we2th, we2tl, skp, 2 * N, DO, DH, 64);
        skredTS_kernel<<<2 * N / 64, 256, 0, stream>>>(
            skp, aE2, wh2buf, t64a, t64b, s1, s2, N, 8);
        att2_kernel<<<2 * N, 256, 0, stream>>>(
            maskF, maskS, s1, s2, N, attF, attS, N);
        tgemm_skd<<<dim3(1, 64, 8), 256, 0, stream>>>(
            attF, t64a, t64b, skp, 2 * N, N, DO, N, 512);
        skred_kernel<true><<<(2 * N * DO + 255) / 256, 256, 0, stream>>>(
            skp, h2out, 2 * N * DO, 8);
    };

    // ---- prep ----
    bitpack_kernel<<<(N * (N / 32) + 255) / 256, 256, 0, stream>>>(adjF, maskF, N * (N / 32));
    bitpack_kernel<<<(N * (N / 32) + 255) / 256, 256, 0, stream>>>(adjS, maskS, N * (N / 32));
    splitA_kernel<<<dim3((DINP + 255) / 256, N), 256, 0, stream>>>(x, xh, xl, DIN, DINP);
    splitBT_kernel<<<dim3((DH + 31) / 32, (DINP + 31) / 32), 256, 0, stream>>>(We1, we1th, we1tl, DIN, DH, DINP);
    splitBT_kernel<<<dim3((DO + 31) / 32, (DH + 31) / 32), 256, 0, stream>>>(We2, we2th, we2tl, DH, DO, DH);
    splitBT_kernel<<<dim3((DH + 31) / 32, (DO + 31) / 32), 256, 0, stream>>>(Wd1, wd1th, wd1tl, DO, DH, DO);
    splitBT_kernel<<<dim3((DIN + 31) / 32, (DH + 31) / 32), 256, 0, stream>>>(Wd2, wd2th, wd2tl, DH, DIN, DH);

    // ---- encoder layer 1 ----
    tgemm2<true, false><<<grid(N, DH), 256, 0, stream>>>(
        xh, xl, we1th, we1tl, wh1x, N, DH, DINP, DINP);
    tr(wh1x, t512, N, DH);
    scores(wh1x, DH, DH, aE1);
    att2_kernel<<<2 * N, 256, 0, stream>>>(maskF, maskS, s1, s2, 0, attF, attS, N);
    gatt(attF, t512, h1, 2 * N, DH);             // h1f|h1s stacked

    // ---- encoder layer 2 (stacked) ----
    layer2(h1, wh2, h2);

    // ---- fuse -> emb_latent + alpha + eh/el split ----
    fuse_kernel<<<N, 64, 0, stream>>>(h2f, h2s, Womega, Uomega, out_emb, out_alpha, eh, el);

    // ---- decoder layer 1 (spatial adj) ----
    tgemm2<true, false><<<grid(N, DH), 256, 0, stream>>>(
        eh, el, wd1th, wd1tl, whd1, N, DH, DO, DO);
    tr(whd1, td1, N, DH);
    scores(whd1, DH, DH, aD1);
    att_kernel<<<N, 256, 0, stream>>>(maskS, s1, s2, attS, N);
    gatt(attS, td1, d1b, N, DH);

    // ---- decoder layer 2 (spatial adj); recon f32 + hi/lo split ----
    tgemm2<false, false><<<grid(N, DIN), 256, 0, stream>>>(
        d1b, nullptr, wd2th, wd2tl, whd2, N, DIN, DH, DH);
    tr(whd2, td2, N, DIN);
    scores(whd2, DIN, DIN, aD2);
    att_kernel<<<N, 256, 0, stream>>>(maskS, s1, s2, attS, N);
    tgemm<true, true, true><<<grid(N, DIN), 256, 0, stream>>>(
        attS, td2, out_recon, N, DIN, N, xh, xl, DINP);

    // ---- corr encoder layer 1 (A = recon split in xh/xl) ----
    tgemm2<true, false><<<grid(N, DH), 256, 0, stream>>>(
        xh, xl, we1th, we1tl, whc1, N, DH, DINP, DINP);
    tr(whc1, t512, N, DH);
    scores(whc1, DH, DH, aE1);
    att2_kernel<<<2 * N, 256, 0, stream>>>(maskF, maskS, s1, s2, 0, attF, attS, N);
    gatt(attF, t512, h1, 2 * N, DH);             // c1f|c1s stacked

    // ---- corr encoder layer 2 (stacked) ----
    layer2(h1, wh2, h2);

    // ---- fuse -> corr ----
    fuse_kernel<<<N, 64, 0, stream>>>(h2f, h2s, Womega, Uomega, out_corr, nullptr, nullptr, nullptr);
}